// Round 4
// baseline (1431.767 us; speedup 1.0000x reference)
//
#include <hip/hip_runtime.h>
#include <hip/hip_bf16.h>
#include <cstdint>
#include <cstddef>

// B=64, D=512, T=1024, L=512
// prep:  xt[b][t][d] bf16 ; W1t[l][d] bf16 ; W2t[n=1536][k=1024] bf16 ; il bf16
// K1:    z = LN(cos(xt @ rff_w + b))        (MFMA BM=32 BN=512, fused LN,
//                                            LDS-staged vectorized z store)
// K2:    gates = act([z_t||z_prev] @ W2t^T) (MFMA, fp32 out)
// scan (segmented): k3a summaries -> k3b combine -> k3c emit + transpose

typedef float f32x4 __attribute__((ext_vector_type(4)));
typedef short s16x8 __attribute__((ext_vector_type(8)));

__device__ __forceinline__ void gload_lds16(const void* g, void* l) {
  __builtin_amdgcn_global_load_lds(
      (const __attribute__((address_space(1))) void*)g,
      (__attribute__((address_space(3))) void*)l, 16, 0, 0);
}
__device__ __forceinline__ ushort f2bf(float f) {
  uint32_t u = __float_as_uint(f);
  return (ushort)((u + 0x7FFF + ((u >> 16) & 1)) >> 16);  // RNE
}
__device__ __forceinline__ float bf2f(ushort s) {
  return __uint_as_float(((uint32_t)s) << 16);
}

// ------------------------------------------------ prep: transpose fp32 -> bf16
__global__ __launch_bounds__(256) void transpose_cvt(
    const float* __restrict__ src, long long srcZ, int src_ld,
    ushort* __restrict__ dst, long long dstZ, int dst_ld)
{
  __shared__ float tile[32][33];
  src += (size_t)blockIdx.z * srcZ;
  dst += (size_t)blockIdx.z * dstZ;
  const int c0 = blockIdx.x * 32, r0 = blockIdx.y * 32;
  const int tx = threadIdx.x & 31, ty = threadIdx.x >> 5;
#pragma unroll
  for (int i = 0; i < 4; ++i)
    tile[ty + i * 8][tx] = src[(size_t)(r0 + ty + i * 8) * src_ld + c0 + tx];
  __syncthreads();
#pragma unroll
  for (int i = 0; i < 4; ++i)
    dst[(size_t)(c0 + ty + i * 8) * dst_ld + r0 + tx] = f2bf(tile[tx][ty + i * 8]);
}

__global__ void cvt_bf16(const float* __restrict__ src, ushort* __restrict__ dst, int n) {
  const int i = blockIdx.x * 256 + threadIdx.x;
  if (i < n) dst[i] = f2bf(src[i]);
}

// ------------------------------------------------ K1: MFMA GEMM + cos + fused LN
// A: xt bf16 [65536][512] (k contig). Bt: W1t bf16 [512][512] (k contig).
// grid (2048): block = 32 rows x 512 cols. 4 waves, wave = 32x128 (wc = wid).
__global__ __launch_bounds__(256) void k1_mfma(
    const ushort* __restrict__ A, const ushort* __restrict__ Bt,
    const float* __restrict__ bias, ushort* __restrict__ Z)
{
  __shared__ __align__(16) short As[32 * 32];     // 2 KB
  __shared__ __align__(16) short Bs[512 * 32];    // 32 KB (reused as z tile)
  __shared__ float redS[4][32], redS2[4][32], redM[32], redI[32];
  const int tid = threadIdx.x;
  const int lane = tid & 63, wid = tid >> 6;
  const int fr = lane & 15, fq = lane >> 4;
  const int r0 = blockIdx.x * 32;

  f32x4 acc[2][8];
#pragma unroll
  for (int m = 0; m < 2; ++m)
#pragma unroll
    for (int n = 0; n < 8; ++n)
#pragma unroll
      for (int j = 0; j < 4; ++j) acc[m][n][j] = 0.f;

  for (int k0 = 0; k0 < 512; k0 += 32) {
    // B tile: 512 rows x 32 k = 2048 x 16B chunks, 8 per thread.
#pragma unroll
    for (int p = 0; p < 8; ++p) {
      const int c = p * 256 + tid;
      gload_lds16(Bt + (size_t)(c >> 2) * 512 + k0 + (c & 3) * 8, &Bs[c * 8]);
    }
    // A tile: 32 rows x 32 k = 128 chunks, waves 0-1 only.
    if (tid < 128) {
      gload_lds16(A + (size_t)(r0 + (tid >> 2)) * 512 + k0 + (tid & 3) * 8,
                  &As[tid * 8]);
    }
    __syncthreads();
    s16x8 a[2], b[8];
#pragma unroll
    for (int m = 0; m < 2; ++m)
      a[m] = *(const s16x8*)&As[(m * 16 + fr) * 32 + fq * 8];
#pragma unroll
    for (int n = 0; n < 8; ++n)
      b[n] = *(const s16x8*)&Bs[(wid * 128 + n * 16 + fr) * 32 + fq * 8];
#pragma unroll
    for (int m = 0; m < 2; ++m)
#pragma unroll
      for (int n = 0; n < 8; ++n)
        acc[m][n] = __builtin_amdgcn_mfma_f32_16x16x32_bf16(a[m], b[n], acc[m][n], 0, 0, 0);
    __syncthreads();
  }

  // u = cos(acc + bias); per-row partial sums over this lane's 8 cols.
  float ps[2][4], ps2[2][4];
#pragma unroll
  for (int m = 0; m < 2; ++m)
#pragma unroll
    for (int j = 0; j < 4; ++j) { ps[m][j] = 0.f; ps2[m][j] = 0.f; }
#pragma unroll
  for (int n = 0; n < 8; ++n) {
    const float bv = bias[wid * 128 + n * 16 + fr];
#pragma unroll
    for (int m = 0; m < 2; ++m)
#pragma unroll
      for (int j = 0; j < 4; ++j) {
        const float v = cosf(acc[m][n][j] + bv);
        acc[m][n][j] = v;
        ps[m][j] += v; ps2[m][j] += v * v;
      }
  }
  // reduce across the 16 fr lanes (bits 0-3 of lane).
#pragma unroll
  for (int m = 0; m < 2; ++m)
#pragma unroll
    for (int j = 0; j < 4; ++j) {
#pragma unroll
      for (int msk = 1; msk < 16; msk <<= 1) {
        ps[m][j]  += __shfl_xor(ps[m][j],  msk);
        ps2[m][j] += __shfl_xor(ps2[m][j], msk);
      }
      if (fr == 0) {
        const int row = m * 16 + fq * 4 + j;
        redS[wid][row] = ps[m][j];
        redS2[wid][row] = ps2[m][j];
      }
    }
  __syncthreads();
  if (tid < 32) {
    const float s  = redS[0][tid] + redS[1][tid] + redS[2][tid] + redS[3][tid];
    const float s2 = redS2[0][tid] + redS2[1][tid] + redS2[2][tid] + redS2[3][tid];
    const float mean = s * (1.f / 512.f);
    const float var = s2 * (1.f / 512.f) - mean * mean;
    redM[tid] = mean;
    redI[tid] = rsqrtf(var + 1e-5f);
  }
  __syncthreads();

  // normalized bf16 tile into Bs (dead), layout == global: [32][512]
  ushort* zs = (ushort*)&Bs[0];
#pragma unroll
  for (int m = 0; m < 2; ++m)
#pragma unroll
    for (int j = 0; j < 4; ++j) {
      const int row = m * 16 + fq * 4 + j;
      const float mean = redM[row], inv = redI[row];
#pragma unroll
      for (int n = 0; n < 8; ++n)
        zs[row * 512 + wid * 128 + n * 16 + fr] = f2bf((acc[m][n][j] - mean) * inv);
    }
  __syncthreads();

  // vectorized copy-out: lane-striped 16B within 4KB stripes (conflict-free).
  ushort* zg = Z + (size_t)r0 * 512;
#pragma unroll
  for (int i = 0; i < 8; ++i)
    *(uint4*)(zg + i * 2048 + tid * 8) = *(const uint4*)&zs[i * 2048 + tid * 8];
}

// ------------------------------------------------ K2: gate GEMM (K=1024, N=1536)
__global__ __launch_bounds__(256) void k2_mfma(
    const ushort* __restrict__ Z, const ushort* __restrict__ Wt,
    const ushort* __restrict__ IL,
    const float* __restrict__ b0, const float* __restrict__ b1,
    const float* __restrict__ b2,
    float* __restrict__ gates, int tc, int Tc)
{
  __shared__ __align__(16) short As[128 * 32];
  __shared__ __align__(16) short Bs[128 * 32];
  const int tid = threadIdx.x;
  const int lane = tid & 63, wid = tid >> 6;
  const int nb = Tc >> 7;
  const int b = blockIdx.y / nb, tb = blockIdx.y % nb;
  const int r0g = b * 1024 + tc + tb * 128;
  const int r0c = b * Tc + tb * 128;
  const int n0 = blockIdx.x * 128;
  const int wr = wid >> 1, wc = wid & 1;
  const int fr = lane & 15, fq = lane >> 4;
  const int srow = wid * 32 + (lane >> 2);
  const int scol = (lane & 3) * 8;

  f32x4 acc[4][4];
#pragma unroll
  for (int m = 0; m < 4; ++m)
#pragma unroll
    for (int n = 0; n < 4; ++n)
#pragma unroll
      for (int j = 0; j < 4; ++j) acc[m][n][j] = 0.f;

  for (int k0 = 0; k0 < 1024; k0 += 32) {
#pragma unroll
    for (int p = 0; p < 2; ++p) {
      const int rr = r0g + srow + p * 16;
      const ushort* asrc;
      if (k0 < 512) {
        asrc = Z + (size_t)rr * 512 + k0 + scol;
      } else {
        const ushort* base = ((rr & 1023) == 0) ? IL : (Z + (size_t)(rr - 1) * 512);
        asrc = base + (k0 - 512) + scol;
      }
      gload_lds16(asrc, &As[(wid * 32 + p * 16) * 32]);
      gload_lds16(Wt + (size_t)(n0 + srow + p * 16) * 1024 + k0 + scol,
                  &Bs[(wid * 32 + p * 16) * 32]);
    }
    __syncthreads();
    s16x8 a[4], bfr[4];
#pragma unroll
    for (int m = 0; m < 4; ++m)
      a[m] = *(const s16x8*)&As[(wr * 64 + m * 16 + fr) * 32 + fq * 8];
#pragma unroll
    for (int n = 0; n < 4; ++n)
      bfr[n] = *(const s16x8*)&Bs[(wc * 64 + n * 16 + fr) * 32 + fq * 8];
#pragma unroll
    for (int m = 0; m < 4; ++m)
#pragma unroll
      for (int n = 0; n < 4; ++n)
        acc[m][n] = __builtin_amdgcn_mfma_f32_16x16x32_bf16(a[m], bfr[n], acc[m][n], 0, 0, 0);
    __syncthreads();
  }

  const int sel = n0 >> 9;
  const float* bb = sel == 0 ? b0 : (sel == 1 ? b1 : b2);
#pragma unroll
  for (int n = 0; n < 4; ++n) {
    const int col = n0 + wc * 64 + n * 16 + fr;
    const float bv = bb[col & 511];
#pragma unroll
    for (int m = 0; m < 4; ++m) {
      const int rbase = wr * 64 + m * 16 + fq * 4;
#pragma unroll
      for (int j = 0; j < 4; ++j) {
        const float uu = acc[m][n][j] + bv;
        const float vv = (sel < 2) ? (1.f / (1.f + __expf(-uu)))
                                   : (2.f / (1.f + __expf(-2.f * uu)) - 1.f);
        gates[(size_t)(r0c + rbase + j) * 1536 + col] = vv;
      }
    }
  }
}

// ------------------------------------------------ scan phase A: segment summaries
__global__ __launch_bounds__(256) void k3a_seg(
    const float* __restrict__ gates, float* __restrict__ Aseg,
    float* __restrict__ Bseg, int Tc)
{
  const int l = blockIdx.x * 256 + threadIdx.x;
  const int b = blockIdx.y, s = blockIdx.z;
  const int SEGc = Tc >> 6;
  const float* gb = gates + ((size_t)(b * Tc + s * 64)) * 1536 + l;
  float A = 1.f, c = 0.f;
#pragma unroll 8
  for (int j = 0; j < 64; ++j) {
    const float iv = gb[(size_t)j * 1536];
    const float fv = gb[(size_t)j * 1536 + 512];
    const float gv = gb[(size_t)j * 1536 + 1024];
    A *= fv;
    c = fmaf(fv, c, iv * gv);
  }
  const size_t o = (size_t)(b * SEGc + s) * 512 + l;
  Aseg[o] = A;
  Bseg[o] = c;
}

// ------------------------------------------------ scan phase B: combine segments
__global__ __launch_bounds__(512) void k3b_comb(
    const float* __restrict__ Aseg, const float* __restrict__ Bseg,
    const float* __restrict__ initc, float* __restrict__ cstart,
    float* __restrict__ cbuf, int tc, int Tc)
{
  const int b = blockIdx.x, l = threadIdx.x;
  const int SEGc = Tc >> 6;
  float c = (tc == 0) ? initc[l] : cbuf[b * 512 + l];
  for (int s = 0; s < SEGc; ++s) {
    const size_t o = (size_t)(b * SEGc + s) * 512 + l;
    cstart[o] = c;
    c = fmaf(Aseg[o], c, Bseg[o]);
  }
  cbuf[b * 512 + l] = c;
}

// ------------------------------------------------ scan phase C: emit outputs
__global__ __launch_bounds__(128) void k3c_emit(
    const float* __restrict__ gates, const ushort* __restrict__ Z,
    const float* __restrict__ cstart, float* __restrict__ out,
    int tc, int Tc)
{
  __shared__ float tile[128][65];
  const int tid = threadIdx.x;
  const int l0 = blockIdx.x * 128;
  const int b = blockIdx.y, s = blockIdx.z;
  const int SEGc = Tc >> 6;
  const int l = l0 + tid;

  float c = cstart[(size_t)(b * SEGc + s) * 512 + l];
  const float* gb = gates + ((size_t)(b * Tc + s * 64)) * 1536 + l;
  const ushort* zb = Z + ((size_t)(b * 1024 + tc + s * 64)) * 512 + l;
#pragma unroll 8
  for (int j = 0; j < 64; ++j) {
    const float iv = gb[(size_t)j * 1536];
    const float fv = gb[(size_t)j * 1536 + 512];
    const float gv = gb[(size_t)j * 1536 + 1024];
    const float zv = bf2f(zb[(size_t)j * 512]);
    c = fmaf(fv, c, iv * gv);
    tile[tid][j] = sinf(zv) * c;
  }
  __syncthreads();
  const int col = tid & 63, rhalf = tid >> 6;
  const size_t obase = ((size_t)b * 512 + l0) * 1024 + (size_t)(tc + s * 64) + col;
#pragma unroll
  for (int p = 0; p < 64; ++p) {
    const int row = rhalf + p * 2;
    out[obase + (size_t)row * 1024] = tile[row][col];
  }
}

// ------------------------------------------------ launcher
extern "C" void kernel_launch(void* const* d_in, const int* in_sizes, int n_in,
                              void* d_out, int out_size, void* d_ws, size_t ws_size,
                              hipStream_t stream)
{
  const float* x  = (const float*)d_in[0];
  const float* W  = (const float*)d_in[1];
  const float* rb = (const float*)d_in[2];
  const float* wi = (const float*)d_in[3];
  const float* wf = (const float*)d_in[4];
  const float* wc = (const float*)d_in[5];
  const float* ri = (const float*)d_in[6];
  const float* rf = (const float*)d_in[7];
  const float* rc = (const float*)d_in[8];
  const float* bi = (const float*)d_in[9];
  const float* bfo = (const float*)d_in[10];
  const float* bc = (const float*)d_in[11];
  const float* il = (const float*)d_in[12];
  const float* ic = (const float*)d_in[13];
  float* out = (float*)d_out;

  char* ws = (char*)d_ws;
  size_t off = 0;
  auto alloc = [&](size_t bytes) -> void* {
    void* p = ws + off;
    off = (off + bytes + 255) & ~(size_t)255;
    return p;
  };
  ushort* z    = (ushort*)alloc((size_t)65536 * 512 * 2);   // 67.1 MB
  ushort* W1t  = (ushort*)alloc((size_t)512 * 512 * 2);
  ushort* W2t  = (ushort*)alloc((size_t)1536 * 1024 * 2);
  ushort* ilb  = (ushort*)alloc(512 * 2);
  float*  cbuf = (float*)alloc((size_t)64 * 512 * 4);
  float*  Aseg = (float*)alloc((size_t)64 * 16 * 512 * 4);  // 2 MB
  float*  Bseg = (float*)alloc((size_t)64 * 16 * 512 * 4);
  float*  cstart = (float*)alloc((size_t)64 * 16 * 512 * 4);
  const size_t fixed_end = off;
  ushort* xt   = (ushort*)alloc((size_t)65536 * 512 * 2);   // dead after K1
  float* gates = (float*)(ws + fixed_end);                  // aliases xt region

  int Tc = 1024;
  while (Tc > 128 && fixed_end + (size_t)64 * Tc * 1536 * 4 > ws_size) Tc >>= 1;

  // prep: weights
  transpose_cvt<<<dim3(16, 16, 1), 256, 0, stream>>>(W, 0, 512, W1t, 0, 512);
  const float* gw[6] = {wi, ri, wf, rf, wc, rc};
  for (int s = 0; s < 3; ++s) {
    transpose_cvt<<<dim3(16, 16, 1), 256, 0, stream>>>(
        gw[s * 2 + 0], 0, 512, W2t + (size_t)s * 512 * 1024, 0, 1024);
    transpose_cvt<<<dim3(16, 16, 1), 256, 0, stream>>>(
        gw[s * 2 + 1], 0, 512, W2t + (size_t)s * 512 * 1024 + 512, 0, 1024);
  }
  cvt_bf16<<<2, 256, 0, stream>>>(il, ilb, 512);
  transpose_cvt<<<dim3(32, 16, 64), 256, 0, stream>>>(
      x, (long long)512 * 1024, 1024, xt, (long long)1024 * 512, 512);

  k1_mfma<<<dim3(2048), 256, 0, stream>>>(xt, W1t, rb, z);

  for (int tc = 0; tc < 1024; tc += Tc) {
    const int SEGc = Tc >> 6;
    k2_mfma<<<dim3(12, 64 * (Tc >> 7)), 256, 0, stream>>>(
        z, W2t, ilb, bi, bfo, bc, gates, tc, Tc);
    k3a_seg<<<dim3(2, 64, SEGc), 256, 0, stream>>>(gates, Aseg, Bseg, Tc);
    k3b_comb<<<64, 512, 0, stream>>>(Aseg, Bseg, ic, cstart, cbuf, tc, Tc);
    k3c_emit<<<dim3(4, 64, SEGc), 128, 0, stream>>>(gates, z, cstart, out, tc, Tc);
  }
}

// Round 5
// 1229.603 us; speedup vs baseline: 1.1644x; 1.1644x over previous
//
#include <hip/hip_runtime.h>
#include <hip/hip_bf16.h>
#include <hip/hip_fp16.h>
#include <cstdint>
#include <cstddef>

// B=64, D=512, T=1024, L=512
// prep:  xt[b][t][d] bf16 ; W1t[l][d] bf16 ; W2t[n=1536][k=1024] bf16 ; il bf16
// K1:    z = LN(cos(xt @ rff_w + b))        (MFMA BM=32 BN=512, fused LN,
//                                            LDS-staged vectorized z store)
// K2:    gates = act([z_t||z_prev] @ W2t^T) (MFMA, fp16 out)
// scan (segmented): k3a summaries -> k3b combine -> k3c emit + transpose

typedef float f32x4 __attribute__((ext_vector_type(4)));
typedef short s16x8 __attribute__((ext_vector_type(8)));

__device__ __forceinline__ void gload_lds16(const void* g, void* l) {
  __builtin_amdgcn_global_load_lds(
      (const __attribute__((address_space(1))) void*)g,
      (__attribute__((address_space(3))) void*)l, 16, 0, 0);
}
__device__ __forceinline__ ushort f2bf(float f) {
  uint32_t u = __float_as_uint(f);
  return (ushort)((u + 0x7FFF + ((u >> 16) & 1)) >> 16);  // RNE
}
__device__ __forceinline__ float bf2f(ushort s) {
  return __uint_as_float(((uint32_t)s) << 16);
}
__device__ __forceinline__ ushort f2h(float f) {
  return __half_as_ushort(__float2half(f));
}
__device__ __forceinline__ float h2f(ushort s) {
  return __half2float(__ushort_as_half(s));
}

// ------------------------------------------------ prep: transpose fp32 -> bf16
__global__ __launch_bounds__(256) void transpose_cvt(
    const float* __restrict__ src, long long srcZ, int src_ld,
    ushort* __restrict__ dst, long long dstZ, int dst_ld)
{
  __shared__ float tile[32][33];
  src += (size_t)blockIdx.z * srcZ;
  dst += (size_t)blockIdx.z * dstZ;
  const int c0 = blockIdx.x * 32, r0 = blockIdx.y * 32;
  const int tx = threadIdx.x & 31, ty = threadIdx.x >> 5;
#pragma unroll
  for (int i = 0; i < 4; ++i)
    tile[ty + i * 8][tx] = src[(size_t)(r0 + ty + i * 8) * src_ld + c0 + tx];
  __syncthreads();
#pragma unroll
  for (int i = 0; i < 4; ++i)
    dst[(size_t)(c0 + ty + i * 8) * dst_ld + r0 + tx] = f2bf(tile[tx][ty + i * 8]);
}

__global__ void cvt_bf16(const float* __restrict__ src, ushort* __restrict__ dst, int n) {
  const int i = blockIdx.x * 256 + threadIdx.x;
  if (i < n) dst[i] = f2bf(src[i]);
}

// ------------------------------------------------ K1: MFMA GEMM + cos + fused LN
// A: xt bf16 [65536][512] (k contig). Bt: W1t bf16 [512][512] (k contig).
// grid (2048): block = 32 rows x 512 cols. 4 waves, wave = 32x128 (wc = wid).
// __launch_bounds__(256, 2): 256-reg cap -> no acc spill (round-4 lesson:
// without the floor, the compiler targeted ~64 regs and spilled acc -> 3.7 GB
// of scratch traffic).
__global__ __launch_bounds__(256, 2) void k1_mfma(
    const ushort* __restrict__ A, const ushort* __restrict__ Bt,
    const float* __restrict__ bias, ushort* __restrict__ Z)
{
  __shared__ __align__(16) short As[32 * 32];     // 2 KB
  __shared__ __align__(16) short Bs[512 * 32];    // 32 KB (reused as z tile)
  __shared__ float redS[4][32], redS2[4][32], redM[32], redI[32];
  const int tid = threadIdx.x;
  const int lane = tid & 63, wid = tid >> 6;
  const int fr = lane & 15, fq = lane >> 4;
  const int r0 = blockIdx.x * 32;

  f32x4 acc[2][8];
#pragma unroll
  for (int m = 0; m < 2; ++m)
#pragma unroll
    for (int n = 0; n < 8; ++n)
#pragma unroll
      for (int j = 0; j < 4; ++j) acc[m][n][j] = 0.f;

  for (int k0 = 0; k0 < 512; k0 += 32) {
    // B tile: 512 rows x 32 k = 2048 x 16B chunks, 8 per thread.
#pragma unroll
    for (int p = 0; p < 8; ++p) {
      const int c = p * 256 + tid;
      gload_lds16(Bt + (size_t)(c >> 2) * 512 + k0 + (c & 3) * 8, &Bs[c * 8]);
    }
    // A tile: 32 rows x 32 k = 128 chunks, waves 0-1 only.
    if (tid < 128) {
      gload_lds16(A + (size_t)(r0 + (tid >> 2)) * 512 + k0 + (tid & 3) * 8,
                  &As[tid * 8]);
    }
    __syncthreads();
    s16x8 a[2];
#pragma unroll
    for (int m = 0; m < 2; ++m)
      a[m] = *(const s16x8*)&As[(m * 16 + fr) * 32 + fq * 8];
    // two half-groups of 4 B-fragments to limit live VGPRs
#pragma unroll
    for (int h = 0; h < 2; ++h) {
      s16x8 b[4];
#pragma unroll
      for (int n = 0; n < 4; ++n)
        b[n] = *(const s16x8*)&Bs[(wid * 128 + (h * 4 + n) * 16 + fr) * 32 + fq * 8];
#pragma unroll
      for (int m = 0; m < 2; ++m)
#pragma unroll
        for (int n = 0; n < 4; ++n)
          acc[m][h * 4 + n] =
              __builtin_amdgcn_mfma_f32_16x16x32_bf16(a[m], b[n], acc[m][h * 4 + n], 0, 0, 0);
    }
    __syncthreads();
  }

  // u = cos(acc + bias); per-row partial sums over this lane's 8 cols.
  float ps[2][4], ps2[2][4];
#pragma unroll
  for (int m = 0; m < 2; ++m)
#pragma unroll
    for (int j = 0; j < 4; ++j) { ps[m][j] = 0.f; ps2[m][j] = 0.f; }
#pragma unroll
  for (int n = 0; n < 8; ++n) {
    const float bv = bias[wid * 128 + n * 16 + fr];
#pragma unroll
    for (int m = 0; m < 2; ++m)
#pragma unroll
      for (int j = 0; j < 4; ++j) {
        const float v = cosf(acc[m][n][j] + bv);
        acc[m][n][j] = v;
        ps[m][j] += v; ps2[m][j] += v * v;
      }
  }
  // reduce across the 16 fr lanes (bits 0-3 of lane).
#pragma unroll
  for (int m = 0; m < 2; ++m)
#pragma unroll
    for (int j = 0; j < 4; ++j) {
#pragma unroll
      for (int msk = 1; msk < 16; msk <<= 1) {
        ps[m][j]  += __shfl_xor(ps[m][j],  msk);
        ps2[m][j] += __shfl_xor(ps2[m][j], msk);
      }
      if (fr == 0) {
        const int row = m * 16 + fq * 4 + j;
        redS[wid][row] = ps[m][j];
        redS2[wid][row] = ps2[m][j];
      }
    }
  __syncthreads();
  if (tid < 32) {
    const float s  = redS[0][tid] + redS[1][tid] + redS[2][tid] + redS[3][tid];
    const float s2 = redS2[0][tid] + redS2[1][tid] + redS2[2][tid] + redS2[3][tid];
    const float mean = s * (1.f / 512.f);
    const float var = s2 * (1.f / 512.f) - mean * mean;
    redM[tid] = mean;
    redI[tid] = rsqrtf(var + 1e-5f);
  }
  __syncthreads();

  // normalized bf16 tile into Bs (dead), layout == global: [32][512]
  ushort* zs = (ushort*)&Bs[0];
#pragma unroll
  for (int m = 0; m < 2; ++m)
#pragma unroll
    for (int j = 0; j < 4; ++j) {
      const int row = m * 16 + fq * 4 + j;
      const float mean = redM[row], inv = redI[row];
#pragma unroll
      for (int n = 0; n < 8; ++n)
        zs[row * 512 + wid * 128 + n * 16 + fr] = f2bf((acc[m][n][j] - mean) * inv);
    }
  __syncthreads();

  // vectorized copy-out: lane-striped 16B (conflict-free, full sectors).
  ushort* zg = Z + (size_t)r0 * 512;
#pragma unroll
  for (int i = 0; i < 8; ++i)
    *(uint4*)(zg + i * 2048 + tid * 8) = *(const uint4*)&zs[i * 2048 + tid * 8];
}

// ------------------------------------------------ K2: gate GEMM (K=1024, N=1536)
__global__ __launch_bounds__(256) void k2_mfma(
    const ushort* __restrict__ Z, const ushort* __restrict__ Wt,
    const ushort* __restrict__ IL,
    const float* __restrict__ b0, const float* __restrict__ b1,
    const float* __restrict__ b2,
    ushort* __restrict__ gates, int tc, int Tc)
{
  __shared__ __align__(16) short As[128 * 32];
  __shared__ __align__(16) short Bs[128 * 32];
  const int tid = threadIdx.x;
  const int lane = tid & 63, wid = tid >> 6;
  const int nb = Tc >> 7;
  const int b = blockIdx.y / nb, tb = blockIdx.y % nb;
  const int r0g = b * 1024 + tc + tb * 128;
  const int r0c = b * Tc + tb * 128;
  const int n0 = blockIdx.x * 128;
  const int wr = wid >> 1, wc = wid & 1;
  const int fr = lane & 15, fq = lane >> 4;
  const int srow = wid * 32 + (lane >> 2);
  const int scol = (lane & 3) * 8;

  f32x4 acc[4][4];
#pragma unroll
  for (int m = 0; m < 4; ++m)
#pragma unroll
    for (int n = 0; n < 4; ++n)
#pragma unroll
      for (int j = 0; j < 4; ++j) acc[m][n][j] = 0.f;

  for (int k0 = 0; k0 < 1024; k0 += 32) {
#pragma unroll
    for (int p = 0; p < 2; ++p) {
      const int rr = r0g + srow + p * 16;
      const ushort* asrc;
      if (k0 < 512) {
        asrc = Z + (size_t)rr * 512 + k0 + scol;
      } else {
        const ushort* base = ((rr & 1023) == 0) ? IL : (Z + (size_t)(rr - 1) * 512);
        asrc = base + (k0 - 512) + scol;
      }
      gload_lds16(asrc, &As[(wid * 32 + p * 16) * 32]);
      gload_lds16(Wt + (size_t)(n0 + srow + p * 16) * 1024 + k0 + scol,
                  &Bs[(wid * 32 + p * 16) * 32]);
    }
    __syncthreads();
    s16x8 a[4], bfr[4];
#pragma unroll
    for (int m = 0; m < 4; ++m)
      a[m] = *(const s16x8*)&As[(wr * 64 + m * 16 + fr) * 32 + fq * 8];
#pragma unroll
    for (int n = 0; n < 4; ++n)
      bfr[n] = *(const s16x8*)&Bs[(wc * 64 + n * 16 + fr) * 32 + fq * 8];
#pragma unroll
    for (int m = 0; m < 4; ++m)
#pragma unroll
      for (int n = 0; n < 4; ++n)
        acc[m][n] = __builtin_amdgcn_mfma_f32_16x16x32_bf16(a[m], bfr[n], acc[m][n], 0, 0, 0);
    __syncthreads();
  }

  const int sel = n0 >> 9;
  const float* bb = sel == 0 ? b0 : (sel == 1 ? b1 : b2);
#pragma unroll
  for (int n = 0; n < 4; ++n) {
    const int col = n0 + wc * 64 + n * 16 + fr;
    const float bv = bb[col & 511];
#pragma unroll
    for (int m = 0; m < 4; ++m) {
      const int rbase = wr * 64 + m * 16 + fq * 4;
#pragma unroll
      for (int j = 0; j < 4; ++j) {
        const float uu = acc[m][n][j] + bv;
        const float vv = (sel < 2) ? (1.f / (1.f + __expf(-uu)))
                                   : (2.f / (1.f + __expf(-2.f * uu)) - 1.f);
        gates[(size_t)(r0c + rbase + j) * 1536 + col] = f2h(vv);
      }
    }
  }
}

// ------------------------------------------------ scan phase A: segment summaries
__global__ __launch_bounds__(256) void k3a_seg(
    const ushort* __restrict__ gates, float* __restrict__ Aseg,
    float* __restrict__ Bseg, int Tc)
{
  const int l = blockIdx.x * 256 + threadIdx.x;
  const int b = blockIdx.y, s = blockIdx.z;
  const int SEGc = Tc >> 6;
  const ushort* gb = gates + ((size_t)(b * Tc + s * 64)) * 1536 + l;
  float A = 1.f, c = 0.f;
#pragma unroll 8
  for (int j = 0; j < 64; ++j) {
    const float iv = h2f(gb[(size_t)j * 1536]);
    const float fv = h2f(gb[(size_t)j * 1536 + 512]);
    const float gv = h2f(gb[(size_t)j * 1536 + 1024]);
    A *= fv;
    c = fmaf(fv, c, iv * gv);
  }
  const size_t o = (size_t)(b * SEGc + s) * 512 + l;
  Aseg[o] = A;
  Bseg[o] = c;
}

// ------------------------------------------------ scan phase B: combine segments
__global__ __launch_bounds__(512) void k3b_comb(
    const float* __restrict__ Aseg, const float* __restrict__ Bseg,
    const float* __restrict__ initc, float* __restrict__ cstart,
    float* __restrict__ cbuf, int tc, int Tc)
{
  const int b = blockIdx.x, l = threadIdx.x;
  const int SEGc = Tc >> 6;
  float c = (tc == 0) ? initc[l] : cbuf[b * 512 + l];
  for (int s = 0; s < SEGc; ++s) {
    const size_t o = (size_t)(b * SEGc + s) * 512 + l;
    cstart[o] = c;
    c = fmaf(Aseg[o], c, Bseg[o]);
  }
  cbuf[b * 512 + l] = c;
}

// ------------------------------------------------ scan phase C: emit outputs
__global__ __launch_bounds__(128) void k3c_emit(
    const ushort* __restrict__ gates, const ushort* __restrict__ Z,
    const float* __restrict__ cstart, float* __restrict__ out,
    int tc, int Tc)
{
  __shared__ float tile[128][65];
  const int tid = threadIdx.x;
  const int l0 = blockIdx.x * 128;
  const int b = blockIdx.y, s = blockIdx.z;
  const int SEGc = Tc >> 6;
  const int l = l0 + tid;

  float c = cstart[(size_t)(b * SEGc + s) * 512 + l];
  const ushort* gb = gates + ((size_t)(b * Tc + s * 64)) * 1536 + l;
  const ushort* zb = Z + ((size_t)(b * 1024 + tc + s * 64)) * 512 + l;
#pragma unroll 8
  for (int j = 0; j < 64; ++j) {
    const float iv = h2f(gb[(size_t)j * 1536]);
    const float fv = h2f(gb[(size_t)j * 1536 + 512]);
    const float gv = h2f(gb[(size_t)j * 1536 + 1024]);
    const float zv = bf2f(zb[(size_t)j * 512]);
    c = fmaf(fv, c, iv * gv);
    tile[tid][j] = sinf(zv) * c;
  }
  __syncthreads();
  const int col = tid & 63, rhalf = tid >> 6;
  const size_t obase = ((size_t)b * 512 + l0) * 1024 + (size_t)(tc + s * 64) + col;
#pragma unroll
  for (int p = 0; p < 64; ++p) {
    const int row = rhalf + p * 2;
    out[obase + (size_t)row * 1024] = tile[row][col];
  }
}

// ------------------------------------------------ launcher
extern "C" void kernel_launch(void* const* d_in, const int* in_sizes, int n_in,
                              void* d_out, int out_size, void* d_ws, size_t ws_size,
                              hipStream_t stream)
{
  const float* x  = (const float*)d_in[0];
  const float* W  = (const float*)d_in[1];
  const float* rb = (const float*)d_in[2];
  const float* wi = (const float*)d_in[3];
  const float* wf = (const float*)d_in[4];
  const float* wc = (const float*)d_in[5];
  const float* ri = (const float*)d_in[6];
  const float* rf = (const float*)d_in[7];
  const float* rc = (const float*)d_in[8];
  const float* bi = (const float*)d_in[9];
  const float* bfo = (const float*)d_in[10];
  const float* bc = (const float*)d_in[11];
  const float* il = (const float*)d_in[12];
  const float* ic = (const float*)d_in[13];
  float* out = (float*)d_out;

  char* ws = (char*)d_ws;
  size_t off = 0;
  auto alloc = [&](size_t bytes) -> void* {
    void* p = ws + off;
    off = (off + bytes + 255) & ~(size_t)255;
    return p;
  };
  ushort* z    = (ushort*)alloc((size_t)65536 * 512 * 2);   // 67.1 MB
  ushort* W1t  = (ushort*)alloc((size_t)512 * 512 * 2);
  ushort* W2t  = (ushort*)alloc((size_t)1536 * 1024 * 2);
  ushort* ilb  = (ushort*)alloc(512 * 2);
  float*  cbuf = (float*)alloc((size_t)64 * 512 * 4);
  float*  Aseg = (float*)alloc((size_t)64 * 16 * 512 * 4);  // 2 MB
  float*  Bseg = (float*)alloc((size_t)64 * 16 * 512 * 4);
  float*  cstart = (float*)alloc((size_t)64 * 16 * 512 * 4);
  const size_t fixed_end = off;
  ushort* xt   = (ushort*)alloc((size_t)65536 * 512 * 2);   // dead after K1
  ushort* gates = (ushort*)(ws + fixed_end);                // aliases xt region

  int Tc = 1024;
  while (Tc > 128 && fixed_end + (size_t)64 * Tc * 1536 * 2 > ws_size) Tc >>= 1;

  // prep: weights
  transpose_cvt<<<dim3(16, 16, 1), 256, 0, stream>>>(W, 0, 512, W1t, 0, 512);
  const float* gw[6] = {wi, ri, wf, rf, wc, rc};
  for (int s = 0; s < 3; ++s) {
    transpose_cvt<<<dim3(16, 16, 1), 256, 0, stream>>>(
        gw[s * 2 + 0], 0, 512, W2t + (size_t)s * 512 * 1024, 0, 1024);
    transpose_cvt<<<dim3(16, 16, 1), 256, 0, stream>>>(
        gw[s * 2 + 1], 0, 512, W2t + (size_t)s * 512 * 1024 + 512, 0, 1024);
  }
  cvt_bf16<<<2, 256, 0, stream>>>(il, ilb, 512);
  transpose_cvt<<<dim3(32, 16, 64), 256, 0, stream>>>(
      x, (long long)512 * 1024, 1024, xt, (long long)1024 * 512, 512);

  k1_mfma<<<dim3(2048), 256, 0, stream>>>(xt, W1t, rb, z);

  for (int tc = 0; tc < 1024; tc += Tc) {
    const int SEGc = Tc >> 6;
    k2_mfma<<<dim3(12, 64 * (Tc >> 7)), 256, 0, stream>>>(
        z, W2t, ilb, bi, bfo, bc, gates, tc, Tc);
    k3a_seg<<<dim3(2, 64, SEGc), 256, 0, stream>>>(gates, Aseg, Bseg, Tc);
    k3b_comb<<<64, 512, 0, stream>>>(Aseg, Bseg, ic, cstart, cbuf, tc, Tc);
    k3c_emit<<<dim3(4, 64, SEGc), 128, 0, stream>>>(gates, z, cstart, out, tc, Tc);
  }
}

// Round 6
// 673.206 us; speedup vs baseline: 2.1268x; 1.8265x over previous
//
#include <hip/hip_runtime.h>
#include <hip/hip_bf16.h>
#include <hip/hip_fp16.h>
#include <cstdint>
#include <cstddef>

// B=64, D=512, T=1024, L=512
// prep:  xt[b][t][d] bf16 ; W1t[l][d] bf16 ; W2t[n=1536][k=1024] bf16 ; il bf16
// K1:    z = LN(cos(xt @ rff_w + b))        (MFMA BM=32 BN=512, fused LN)
// K2:    gates = act([z_t||z_prev] @ W2t^T) (MFMA, fp16 out)
// scan (segmented): k3a summaries -> k3b combine -> k3c emit + transpose
//
// ROUND-6 KEY CHANGE: accumulators/fragments are NAMED variables, not arrays.
// f32x4 acc[M][N] arrays were never SROA-promoted -> lived in scratch ->
// 2.2-2.4 GB of per-K-iter RMW scratch traffic in every MFMA kernel so far
// (VGPR_Count 52-76 + GB-scale WRITE_SIZE = pre-RA stack alloc signature).

typedef float f32x4 __attribute__((ext_vector_type(4)));
typedef short s16x8 __attribute__((ext_vector_type(8)));

__device__ __forceinline__ void gload_lds16(const void* g, void* l) {
  __builtin_amdgcn_global_load_lds(
      (const __attribute__((address_space(1))) void*)g,
      (__attribute__((address_space(3))) void*)l, 16, 0, 0);
}
__device__ __forceinline__ ushort f2bf(float f) {
  uint32_t u = __float_as_uint(f);
  return (ushort)((u + 0x7FFF + ((u >> 16) & 1)) >> 16);  // RNE
}
__device__ __forceinline__ float bf2f(ushort s) {
  return __uint_as_float(((uint32_t)s) << 16);
}
__device__ __forceinline__ ushort f2h(float f) {
  return __half_as_ushort(__float2half(f));
}
__device__ __forceinline__ float h2f(ushort s) {
  return __half2float(__ushort_as_half(s));
}

#define MF(d, a, b) d = __builtin_amdgcn_mfma_f32_16x16x32_bf16(a, b, d, 0, 0, 0);

// ------------------------------------------------ prep: transpose fp32 -> bf16
__global__ __launch_bounds__(256) void transpose_cvt(
    const float* __restrict__ src, long long srcZ, int src_ld,
    ushort* __restrict__ dst, long long dstZ, int dst_ld)
{
  __shared__ float tile[32][33];
  src += (size_t)blockIdx.z * srcZ;
  dst += (size_t)blockIdx.z * dstZ;
  const int c0 = blockIdx.x * 32, r0 = blockIdx.y * 32;
  const int tx = threadIdx.x & 31, ty = threadIdx.x >> 5;
#pragma unroll
  for (int i = 0; i < 4; ++i)
    tile[ty + i * 8][tx] = src[(size_t)(r0 + ty + i * 8) * src_ld + c0 + tx];
  __syncthreads();
#pragma unroll
  for (int i = 0; i < 4; ++i)
    dst[(size_t)(c0 + ty + i * 8) * dst_ld + r0 + tx] = f2bf(tile[tx][ty + i * 8]);
}

__global__ void cvt_bf16(const float* __restrict__ src, ushort* __restrict__ dst, int n) {
  const int i = blockIdx.x * 256 + threadIdx.x;
  if (i < n) dst[i] = f2bf(src[i]);
}

// ------------------------------------------------ K1: MFMA GEMM + cos + fused LN
// grid (2048): block = 32 rows x 512 cols. 4 waves, wave = 32x128 (quarter = wid).
__global__ __launch_bounds__(256, 2) void k1_mfma(
    const ushort* __restrict__ A, const ushort* __restrict__ Bt,
    const float* __restrict__ bias, ushort* __restrict__ Z)
{
  __shared__ __align__(16) short As[32 * 32];     // 2 KB
  __shared__ __align__(16) short Bs[512 * 32];    // 32 KB (reused as z tile)
  __shared__ float redS[4][32], redS2[4][32], redM[32], redI[32];
  const int tid = threadIdx.x;
  const int lane = tid & 63, wid = tid >> 6;
  const int fr = lane & 15, fq = lane >> 4;
  const int r0 = blockIdx.x * 32;

  f32x4 d00 = {0.f,0.f,0.f,0.f}, d01 = d00, d02 = d00, d03 = d00,
        d04 = d00, d05 = d00, d06 = d00, d07 = d00,
        d10 = d00, d11 = d00, d12 = d00, d13 = d00,
        d14 = d00, d15 = d00, d16 = d00, d17 = d00;

  for (int k0 = 0; k0 < 512; k0 += 32) {
#pragma unroll
    for (int p = 0; p < 8; ++p) {
      const int c = p * 256 + tid;
      gload_lds16(Bt + (size_t)(c >> 2) * 512 + k0 + (c & 3) * 8, &Bs[c * 8]);
    }
    if (tid < 128) {
      gload_lds16(A + (size_t)(r0 + (tid >> 2)) * 512 + k0 + (tid & 3) * 8,
                  &As[tid * 8]);
    }
    __syncthreads();
    const s16x8 a0 = *(const s16x8*)&As[(fr) * 32 + fq * 8];
    const s16x8 a1 = *(const s16x8*)&As[(16 + fr) * 32 + fq * 8];
    const s16x8 b0 = *(const s16x8*)&Bs[(wid * 128 + 0 * 16 + fr) * 32 + fq * 8];
    const s16x8 b1 = *(const s16x8*)&Bs[(wid * 128 + 1 * 16 + fr) * 32 + fq * 8];
    const s16x8 b2 = *(const s16x8*)&Bs[(wid * 128 + 2 * 16 + fr) * 32 + fq * 8];
    const s16x8 b3 = *(const s16x8*)&Bs[(wid * 128 + 3 * 16 + fr) * 32 + fq * 8];
    const s16x8 b4 = *(const s16x8*)&Bs[(wid * 128 + 4 * 16 + fr) * 32 + fq * 8];
    const s16x8 b5 = *(const s16x8*)&Bs[(wid * 128 + 5 * 16 + fr) * 32 + fq * 8];
    const s16x8 b6 = *(const s16x8*)&Bs[(wid * 128 + 6 * 16 + fr) * 32 + fq * 8];
    const s16x8 b7 = *(const s16x8*)&Bs[(wid * 128 + 7 * 16 + fr) * 32 + fq * 8];
    MF(d00, a0, b0) MF(d01, a0, b1) MF(d02, a0, b2) MF(d03, a0, b3)
    MF(d04, a0, b4) MF(d05, a0, b5) MF(d06, a0, b6) MF(d07, a0, b7)
    MF(d10, a1, b0) MF(d11, a1, b1) MF(d12, a1, b2) MF(d13, a1, b3)
    MF(d14, a1, b4) MF(d15, a1, b5) MF(d16, a1, b6) MF(d17, a1, b7)
    __syncthreads();
  }

  // u = cos(d + bias); per-row partial sums (named vector accumulators).
  f32x4 ps0 = {0.f,0.f,0.f,0.f}, pq0 = ps0, ps1 = ps0, pq1 = ps0;
#define CB(d, m_, n_) { \
    const float bv = bias[wid * 128 + n_ * 16 + fr]; \
    f32x4 t; \
    _Pragma("unroll") for (int j = 0; j < 4; ++j) t[j] = cosf(d[j] + bv); \
    d = t; ps##m_ += t; pq##m_ += t * t; }
  CB(d00, 0, 0) CB(d01, 0, 1) CB(d02, 0, 2) CB(d03, 0, 3)
  CB(d04, 0, 4) CB(d05, 0, 5) CB(d06, 0, 6) CB(d07, 0, 7)
  CB(d10, 1, 0) CB(d11, 1, 1) CB(d12, 1, 2) CB(d13, 1, 3)
  CB(d14, 1, 4) CB(d15, 1, 5) CB(d16, 1, 6) CB(d17, 1, 7)
#undef CB

  // reduce across the 16 fr lanes (bits 0-3 of lane); deposit per-row sums.
#pragma unroll
  for (int j = 0; j < 4; ++j) {
    float s = ps0[j], s2 = pq0[j];
#pragma unroll
    for (int msk = 1; msk < 16; msk <<= 1) {
      s += __shfl_xor(s, msk); s2 += __shfl_xor(s2, msk);
    }
    if (fr == 0) { redS[wid][fq * 4 + j] = s; redS2[wid][fq * 4 + j] = s2; }
  }
#pragma unroll
  for (int j = 0; j < 4; ++j) {
    float s = ps1[j], s2 = pq1[j];
#pragma unroll
    for (int msk = 1; msk < 16; msk <<= 1) {
      s += __shfl_xor(s, msk); s2 += __shfl_xor(s2, msk);
    }
    if (fr == 0) { redS[wid][16 + fq * 4 + j] = s; redS2[wid][16 + fq * 4 + j] = s2; }
  }
  __syncthreads();
  if (tid < 32) {
    const float s  = redS[0][tid] + redS[1][tid] + redS[2][tid] + redS[3][tid];
    const float s2 = redS2[0][tid] + redS2[1][tid] + redS2[2][tid] + redS2[3][tid];
    const float mean = s * (1.f / 512.f);
    const float var = s2 * (1.f / 512.f) - mean * mean;
    redM[tid] = mean;
    redI[tid] = rsqrtf(var + 1e-5f);
  }
  __syncthreads();

  // normalized bf16 tile into Bs (dead), layout == global: [32][512]
  ushort* zs = (ushort*)&Bs[0];
#define ZST(d, m_, n_) { \
    _Pragma("unroll") for (int j = 0; j < 4; ++j) { \
      const int row = m_ * 16 + fq * 4 + j; \
      zs[row * 512 + wid * 128 + n_ * 16 + fr] = \
          f2bf((d[j] - redM[row]) * redI[row]); } }
  ZST(d00, 0, 0) ZST(d01, 0, 1) ZST(d02, 0, 2) ZST(d03, 0, 3)
  ZST(d04, 0, 4) ZST(d05, 0, 5) ZST(d06, 0, 6) ZST(d07, 0, 7)
  ZST(d10, 1, 0) ZST(d11, 1, 1) ZST(d12, 1, 2) ZST(d13, 1, 3)
  ZST(d14, 1, 4) ZST(d15, 1, 5) ZST(d16, 1, 6) ZST(d17, 1, 7)
#undef ZST
  __syncthreads();

  // vectorized copy-out: lane-striped 16B (full sectors).
  ushort* zg = Z + (size_t)r0 * 512;
#pragma unroll
  for (int i = 0; i < 8; ++i)
    *(uint4*)(zg + i * 2048 + tid * 8) = *(const uint4*)&zs[i * 2048 + tid * 8];
}

// ------------------------------------------------ K2: gate GEMM (K=1024, N=1536)
__global__ __launch_bounds__(256, 2) void k2_mfma(
    const ushort* __restrict__ Z, const ushort* __restrict__ Wt,
    const ushort* __restrict__ IL,
    const float* __restrict__ b0v, const float* __restrict__ b1v,
    const float* __restrict__ b2v,
    ushort* __restrict__ gates, int tc, int Tc)
{
  __shared__ __align__(16) short As[128 * 32];
  __shared__ __align__(16) short Bs[128 * 32];
  const int tid = threadIdx.x;
  const int lane = tid & 63, wid = tid >> 6;
  const int nb = Tc >> 7;
  const int b = blockIdx.y / nb, tb = blockIdx.y % nb;
  const int r0g = b * 1024 + tc + tb * 128;
  const int r0c = b * Tc + tb * 128;
  const int n0 = blockIdx.x * 128;
  const int wr = wid >> 1, wc = wid & 1;
  const int fr = lane & 15, fq = lane >> 4;
  const int srow = wid * 32 + (lane >> 2);
  const int scol = (lane & 3) * 8;

  f32x4 c00 = {0.f,0.f,0.f,0.f}, c01 = c00, c02 = c00, c03 = c00,
        c10 = c00, c11 = c00, c12 = c00, c13 = c00,
        c20 = c00, c21 = c00, c22 = c00, c23 = c00,
        c30 = c00, c31 = c00, c32 = c00, c33 = c00;

  for (int k0 = 0; k0 < 1024; k0 += 32) {
#pragma unroll
    for (int p = 0; p < 2; ++p) {
      const int rr = r0g + srow + p * 16;
      const ushort* asrc;
      if (k0 < 512) {
        asrc = Z + (size_t)rr * 512 + k0 + scol;
      } else {
        const ushort* base = ((rr & 1023) == 0) ? IL : (Z + (size_t)(rr - 1) * 512);
        asrc = base + (k0 - 512) + scol;
      }
      gload_lds16(asrc, &As[(wid * 32 + p * 16) * 32]);
      gload_lds16(Wt + (size_t)(n0 + srow + p * 16) * 1024 + k0 + scol,
                  &Bs[(wid * 32 + p * 16) * 32]);
    }
    __syncthreads();
    const s16x8 a0 = *(const s16x8*)&As[(wr * 64 + 0 * 16 + fr) * 32 + fq * 8];
    const s16x8 a1 = *(const s16x8*)&As[(wr * 64 + 1 * 16 + fr) * 32 + fq * 8];
    const s16x8 a2 = *(const s16x8*)&As[(wr * 64 + 2 * 16 + fr) * 32 + fq * 8];
    const s16x8 a3 = *(const s16x8*)&As[(wr * 64 + 3 * 16 + fr) * 32 + fq * 8];
    const s16x8 b0 = *(const s16x8*)&Bs[(wc * 64 + 0 * 16 + fr) * 32 + fq * 8];
    const s16x8 b1 = *(const s16x8*)&Bs[(wc * 64 + 1 * 16 + fr) * 32 + fq * 8];
    const s16x8 b2 = *(const s16x8*)&Bs[(wc * 64 + 2 * 16 + fr) * 32 + fq * 8];
    const s16x8 b3 = *(const s16x8*)&Bs[(wc * 64 + 3 * 16 + fr) * 32 + fq * 8];
    MF(c00, a0, b0) MF(c01, a0, b1) MF(c02, a0, b2) MF(c03, a0, b3)
    MF(c10, a1, b0) MF(c11, a1, b1) MF(c12, a1, b2) MF(c13, a1, b3)
    MF(c20, a2, b0) MF(c21, a2, b1) MF(c22, a2, b2) MF(c23, a2, b3)
    MF(c30, a3, b0) MF(c31, a3, b1) MF(c32, a3, b2) MF(c33, a3, b3)
    __syncthreads();
  }

  const int sel = n0 >> 9;
  const float* bb = sel == 0 ? b0v : (sel == 1 ? b1v : b2v);
#define EPI(cmn, m_, n_) { \
    const int col = n0 + wc * 64 + n_ * 16 + fr; \
    const float bv = bb[col & 511]; \
    const int rbase = wr * 64 + m_ * 16 + fq * 4; \
    _Pragma("unroll") for (int j = 0; j < 4; ++j) { \
      const float uu = cmn[j] + bv; \
      const float vv = (sel < 2) ? (1.f / (1.f + __expf(-uu))) \
                                 : (2.f / (1.f + __expf(-2.f * uu)) - 1.f); \
      gates[(size_t)(r0c + rbase + j) * 1536 + col] = f2h(vv); } }
  EPI(c00, 0, 0) EPI(c01, 0, 1) EPI(c02, 0, 2) EPI(c03, 0, 3)
  EPI(c10, 1, 0) EPI(c11, 1, 1) EPI(c12, 1, 2) EPI(c13, 1, 3)
  EPI(c20, 2, 0) EPI(c21, 2, 1) EPI(c22, 2, 2) EPI(c23, 2, 3)
  EPI(c30, 3, 0) EPI(c31, 3, 1) EPI(c32, 3, 2) EPI(c33, 3, 3)
#undef EPI
}

// ------------------------------------------------ scan phase A: segment summaries
__global__ __launch_bounds__(256) void k3a_seg(
    const ushort* __restrict__ gates, float* __restrict__ Aseg,
    float* __restrict__ Bseg, int Tc)
{
  const int l = blockIdx.x * 256 + threadIdx.x;
  const int b = blockIdx.y, s = blockIdx.z;
  const int SEGc = Tc >> 6;
  const ushort* gb = gates + ((size_t)(b * Tc + s * 64)) * 1536 + l;
  float A = 1.f, c = 0.f;
#pragma unroll 8
  for (int j = 0; j < 64; ++j) {
    const float iv = h2f(gb[(size_t)j * 1536]);
    const float fv = h2f(gb[(size_t)j * 1536 + 512]);
    const float gv = h2f(gb[(size_t)j * 1536 + 1024]);
    A *= fv;
    c = fmaf(fv, c, iv * gv);
  }
  const size_t o = (size_t)(b * SEGc + s) * 512 + l;
  Aseg[o] = A;
  Bseg[o] = c;
}

// ------------------------------------------------ scan phase B: combine segments
__global__ __launch_bounds__(512) void k3b_comb(
    const float* __restrict__ Aseg, const float* __restrict__ Bseg,
    const float* __restrict__ initc, float* __restrict__ cstart,
    float* __restrict__ cbuf, int tc, int Tc)
{
  const int b = blockIdx.x, l = threadIdx.x;
  const int SEGc = Tc >> 6;
  float c = (tc == 0) ? initc[l] : cbuf[b * 512 + l];
  for (int s = 0; s < SEGc; ++s) {
    const size_t o = (size_t)(b * SEGc + s) * 512 + l;
    cstart[o] = c;
    c = fmaf(Aseg[o], c, Bseg[o]);
  }
  cbuf[b * 512 + l] = c;
}

// ------------------------------------------------ scan phase C: emit outputs
__global__ __launch_bounds__(128) void k3c_emit(
    const ushort* __restrict__ gates, const ushort* __restrict__ Z,
    const float* __restrict__ cstart, float* __restrict__ out,
    int tc, int Tc)
{
  __shared__ float tile[128][65];
  const int tid = threadIdx.x;
  const int l0 = blockIdx.x * 128;
  const int b = blockIdx.y, s = blockIdx.z;
  const int SEGc = Tc >> 6;
  const int l = l0 + tid;

  float c = cstart[(size_t)(b * SEGc + s) * 512 + l];
  const ushort* gb = gates + ((size_t)(b * Tc + s * 64)) * 1536 + l;
  const ushort* zb = Z + ((size_t)(b * 1024 + tc + s * 64)) * 512 + l;
#pragma unroll 8
  for (int j = 0; j < 64; ++j) {
    const float iv = h2f(gb[(size_t)j * 1536]);
    const float fv = h2f(gb[(size_t)j * 1536 + 512]);
    const float gv = h2f(gb[(size_t)j * 1536 + 1024]);
    const float zv = bf2f(zb[(size_t)j * 512]);
    c = fmaf(fv, c, iv * gv);
    tile[tid][j] = sinf(zv) * c;
  }
  __syncthreads();
  const int col = tid & 63, rhalf = tid >> 6;
  const size_t obase = ((size_t)b * 512 + l0) * 1024 + (size_t)(tc + s * 64) + col;
#pragma unroll
  for (int p = 0; p < 64; ++p) {
    const int row = rhalf + p * 2;
    out[obase + (size_t)row * 1024] = tile[row][col];
  }
}

// ------------------------------------------------ launcher
extern "C" void kernel_launch(void* const* d_in, const int* in_sizes, int n_in,
                              void* d_out, int out_size, void* d_ws, size_t ws_size,
                              hipStream_t stream)
{
  const float* x  = (const float*)d_in[0];
  const float* W  = (const float*)d_in[1];
  const float* rb = (const float*)d_in[2];
  const float* wi = (const float*)d_in[3];
  const float* wf = (const float*)d_in[4];
  const float* wc = (const float*)d_in[5];
  const float* ri = (const float*)d_in[6];
  const float* rf = (const float*)d_in[7];
  const float* rc = (const float*)d_in[8];
  const float* bi = (const float*)d_in[9];
  const float* bfo = (const float*)d_in[10];
  const float* bc = (const float*)d_in[11];
  const float* il = (const float*)d_in[12];
  const float* ic = (const float*)d_in[13];
  float* out = (float*)d_out;

  char* ws = (char*)d_ws;
  size_t off = 0;
  auto alloc = [&](size_t bytes) -> void* {
    void* p = ws + off;
    off = (off + bytes + 255) & ~(size_t)255;
    return p;
  };
  ushort* z    = (ushort*)alloc((size_t)65536 * 512 * 2);   // 67.1 MB
  ushort* W1t  = (ushort*)alloc((size_t)512 * 512 * 2);
  ushort* W2t  = (ushort*)alloc((size_t)1536 * 1024 * 2);
  ushort* ilb  = (ushort*)alloc(512 * 2);
  float*  cbuf = (float*)alloc((size_t)64 * 512 * 4);
  float*  Aseg = (float*)alloc((size_t)64 * 16 * 512 * 4);  // 2 MB
  float*  Bseg = (float*)alloc((size_t)64 * 16 * 512 * 4);
  float*  cstart = (float*)alloc((size_t)64 * 16 * 512 * 4);
  const size_t fixed_end = off;
  ushort* xt   = (ushort*)alloc((size_t)65536 * 512 * 2);   // dead after K1
  ushort* gates = (ushort*)(ws + fixed_end);                // aliases xt region

  int Tc = 1024;
  while (Tc > 128 && fixed_end + (size_t)64 * Tc * 1536 * 2 > ws_size) Tc >>= 1;

  // prep: weights
  transpose_cvt<<<dim3(16, 16, 1), 256, 0, stream>>>(W, 0, 512, W1t, 0, 512);
  const float* gw[6] = {wi, ri, wf, rf, wc, rc};
  for (int s = 0; s < 3; ++s) {
    transpose_cvt<<<dim3(16, 16, 1), 256, 0, stream>>>(
        gw[s * 2 + 0], 0, 512, W2t + (size_t)s * 512 * 1024, 0, 1024);
    transpose_cvt<<<dim3(16, 16, 1), 256, 0, stream>>>(
        gw[s * 2 + 1], 0, 512, W2t + (size_t)s * 512 * 1024 + 512, 0, 1024);
  }
  cvt_bf16<<<2, 256, 0, stream>>>(il, ilb, 512);
  transpose_cvt<<<dim3(32, 16, 64), 256, 0, stream>>>(
      x, (long long)512 * 1024, 1024, xt, (long long)1024 * 512, 512);

  k1_mfma<<<dim3(2048), 256, 0, stream>>>(xt, W1t, rb, z);

  for (int tc = 0; tc < 1024; tc += Tc) {
    const int SEGc = Tc >> 6;
    k2_mfma<<<dim3(12, 64 * (Tc >> 7)), 256, 0, stream>>>(
        z, W2t, ilb, bi, bfo, bc, gates, tc, Tc);
    k3a_seg<<<dim3(2, 64, SEGc), 256, 0, stream>>>(gates, Aseg, Bseg, Tc);
    k3b_comb<<<64, 512, 0, stream>>>(Aseg, Bseg, ic, cstart, cbuf, tc, Tc);
    k3c_emit<<<dim3(4, 64, SEGc), 128, 0, stream>>>(gates, z, cstart, out, tc, Tc);
  }
}

// Round 7
// 641.046 us; speedup vs baseline: 2.2335x; 1.0502x over previous
//
#include <hip/hip_runtime.h>
#include <hip/hip_bf16.h>
#include <hip/hip_fp16.h>
#include <cstdint>
#include <cstddef>

// B=64, D=512, T=1024, L=512
// prep:  xt[b][t][d] bf16 ; W1t[l][d] bf16 ; W2t[n=1536][k=1024] bf16 ; il bf16
// K1:    u = cos(xt @ rff_w + b)            (MFMA 128x128, u -> d_out scratch)
// LN:    z = layernorm(u)                   (bf16, one wave per row)
// K2:    gates = act([z_t||z_prev] @ W2t^T) (MFMA 128x128, fp16 out)
// scan (segmented): k3a summaries -> k3b combine -> k3c emit + transpose
//
// LESSON (r4-r6): f32x4 acc[M][N] arrays are NOT SROA-promoted -> scratch RMW
// (GB-scale WRITE_SIZE, VGPR_Count ~60). All accumulators/fragments are NAMED.
// LESSON (r6): scalar 2B stores to distinct rows write-combine fine (+5% amp).

typedef float f32x4 __attribute__((ext_vector_type(4)));
typedef short s16x8 __attribute__((ext_vector_type(8)));

__device__ __forceinline__ void gload_lds16(const void* g, void* l) {
  __builtin_amdgcn_global_load_lds(
      (const __attribute__((address_space(1))) void*)g,
      (__attribute__((address_space(3))) void*)l, 16, 0, 0);
}
__device__ __forceinline__ ushort f2bf(float f) {
  uint32_t u = __float_as_uint(f);
  return (ushort)((u + 0x7FFF + ((u >> 16) & 1)) >> 16);  // RNE
}
__device__ __forceinline__ float bf2f(ushort s) {
  return __uint_as_float(((uint32_t)s) << 16);
}
__device__ __forceinline__ ushort f2h(float f) {
  return __half_as_ushort(__float2half(f));
}
__device__ __forceinline__ float h2f(ushort s) {
  return __half2float(__ushort_as_half(s));
}

#define MF(d, a, b) d = __builtin_amdgcn_mfma_f32_16x16x32_bf16(a, b, d, 0, 0, 0);

// ------------------------------------------------ prep: transpose fp32 -> bf16
__global__ __launch_bounds__(256) void transpose_cvt(
    const float* __restrict__ src, long long srcZ, int src_ld,
    ushort* __restrict__ dst, long long dstZ, int dst_ld)
{
  __shared__ float tile[32][33];
  src += (size_t)blockIdx.z * srcZ;
  dst += (size_t)blockIdx.z * dstZ;
  const int c0 = blockIdx.x * 32, r0 = blockIdx.y * 32;
  const int tx = threadIdx.x & 31, ty = threadIdx.x >> 5;
#pragma unroll
  for (int i = 0; i < 4; ++i)
    tile[ty + i * 8][tx] = src[(size_t)(r0 + ty + i * 8) * src_ld + c0 + tx];
  __syncthreads();
#pragma unroll
  for (int i = 0; i < 4; ++i)
    dst[(size_t)(c0 + ty + i * 8) * dst_ld + r0 + tx] = f2bf(tile[tx][ty + i * 8]);
}

__global__ void cvt_bf16(const float* __restrict__ src, ushort* __restrict__ dst, int n) {
  const int i = blockIdx.x * 256 + threadIdx.x;
  if (i < n) dst[i] = f2bf(src[i]);
}

// ------------------------------------------------ K1: u = cos(xt@W1t^T + bias)
// 128x128 tile, 4 waves 2x2, named accs. grid 2048 1-D, XCD-swizzled.
__global__ __launch_bounds__(256, 2) void k1_mfma(
    const ushort* __restrict__ A, const ushort* __restrict__ Bt,
    const float* __restrict__ bias, ushort* __restrict__ U)
{
  __shared__ __align__(16) short As[128 * 32];
  __shared__ __align__(16) short Bs[128 * 32];
  const int tid = threadIdx.x;
  const int lane = tid & 63, wid = tid >> 6;
  // bijective XCD swizzle: nwg=2048, cpx=256 (nwg%8==0)
  const int orig = blockIdx.x;
  const int swz = (orig & 7) * 256 + (orig >> 3);
  const int n0 = (swz & 3) * 128, r0 = (swz >> 2) * 128;
  const int wr = wid >> 1, wc = wid & 1;
  const int fr = lane & 15, fq = lane >> 4;
  const int srow = wid * 32 + (lane >> 2);
  const int scol = (lane & 3) * 8;

  const ushort* a_0 = A + (size_t)(r0 + srow) * 512 + scol;
  const ushort* a_1 = A + (size_t)(r0 + srow + 16) * 512 + scol;
  const ushort* b_0 = Bt + (size_t)(n0 + srow) * 512 + scol;
  const ushort* b_1 = Bt + (size_t)(n0 + srow + 16) * 512 + scol;

  f32x4 c00 = {0.f,0.f,0.f,0.f}, c01 = c00, c02 = c00, c03 = c00,
        c10 = c00, c11 = c00, c12 = c00, c13 = c00,
        c20 = c00, c21 = c00, c22 = c00, c23 = c00,
        c30 = c00, c31 = c00, c32 = c00, c33 = c00;

  for (int k0 = 0; k0 < 512; k0 += 32) {
    gload_lds16(a_0 + k0, &As[(wid * 32) * 32]);
    gload_lds16(a_1 + k0, &As[(wid * 32 + 16) * 32]);
    gload_lds16(b_0 + k0, &Bs[(wid * 32) * 32]);
    gload_lds16(b_1 + k0, &Bs[(wid * 32 + 16) * 32]);
    __syncthreads();
    const s16x8 a0 = *(const s16x8*)&As[(wr * 64 + 0 * 16 + fr) * 32 + fq * 8];
    const s16x8 a1 = *(const s16x8*)&As[(wr * 64 + 1 * 16 + fr) * 32 + fq * 8];
    const s16x8 a2 = *(const s16x8*)&As[(wr * 64 + 2 * 16 + fr) * 32 + fq * 8];
    const s16x8 a3 = *(const s16x8*)&As[(wr * 64 + 3 * 16 + fr) * 32 + fq * 8];
    const s16x8 b0 = *(const s16x8*)&Bs[(wc * 64 + 0 * 16 + fr) * 32 + fq * 8];
    const s16x8 b1 = *(const s16x8*)&Bs[(wc * 64 + 1 * 16 + fr) * 32 + fq * 8];
    const s16x8 b2 = *(const s16x8*)&Bs[(wc * 64 + 2 * 16 + fr) * 32 + fq * 8];
    const s16x8 b3 = *(const s16x8*)&Bs[(wc * 64 + 3 * 16 + fr) * 32 + fq * 8];
    MF(c00, a0, b0) MF(c01, a0, b1) MF(c02, a0, b2) MF(c03, a0, b3)
    MF(c10, a1, b0) MF(c11, a1, b1) MF(c12, a1, b2) MF(c13, a1, b3)
    MF(c20, a2, b0) MF(c21, a2, b1) MF(c22, a2, b2) MF(c23, a2, b3)
    MF(c30, a3, b0) MF(c31, a3, b1) MF(c32, a3, b2) MF(c33, a3, b3)
    __syncthreads();
  }

#define EPI1(cmn, m_, n_) { \
    const int col = n0 + wc * 64 + n_ * 16 + fr; \
    const float bv = bias[col]; \
    const int rbase = r0 + wr * 64 + m_ * 16 + fq * 4; \
    _Pragma("unroll") for (int j = 0; j < 4; ++j) \
      U[(size_t)(rbase + j) * 512 + col] = f2bf(cosf(cmn[j] + bv)); }
  EPI1(c00, 0, 0) EPI1(c01, 0, 1) EPI1(c02, 0, 2) EPI1(c03, 0, 3)
  EPI1(c10, 1, 0) EPI1(c11, 1, 1) EPI1(c12, 1, 2) EPI1(c13, 1, 3)
  EPI1(c20, 2, 0) EPI1(c21, 2, 1) EPI1(c22, 2, 2) EPI1(c23, 2, 3)
  EPI1(c30, 3, 0) EPI1(c31, 3, 1) EPI1(c32, 3, 2) EPI1(c33, 3, 3)
#undef EPI1
}

// ------------------------------------------------ LN: one wave per 512-row (r2-verified)
__global__ __launch_bounds__(256) void ln_rows(
    const ushort* __restrict__ U, ushort* __restrict__ Z)
{
  const int row = blockIdx.x * 4 + (threadIdx.x >> 6);
  const int lane = threadIdx.x & 63;
  const size_t base = (size_t)row * 512 + lane * 8;
  const uint4 pk = *(const uint4*)(U + base);
  float v[8];
  v[0] = bf2f(pk.x & 0xffff); v[1] = bf2f(pk.x >> 16);
  v[2] = bf2f(pk.y & 0xffff); v[3] = bf2f(pk.y >> 16);
  v[4] = bf2f(pk.z & 0xffff); v[5] = bf2f(pk.z >> 16);
  v[6] = bf2f(pk.w & 0xffff); v[7] = bf2f(pk.w >> 16);
  float s = 0.f, s2 = 0.f;
#pragma unroll
  for (int j = 0; j < 8; ++j) { s += v[j]; s2 += v[j] * v[j]; }
#pragma unroll
  for (int m = 1; m < 64; m <<= 1) { s += __shfl_xor(s, m); s2 += __shfl_xor(s2, m); }
  const float mean = s * (1.f / 512.f);
  const float var = s2 * (1.f / 512.f) - mean * mean;
  const float inv = rsqrtf(var + 1e-5f);
  uint4 o;
  o.x = (uint)f2bf((v[0] - mean) * inv) | ((uint)f2bf((v[1] - mean) * inv) << 16);
  o.y = (uint)f2bf((v[2] - mean) * inv) | ((uint)f2bf((v[3] - mean) * inv) << 16);
  o.z = (uint)f2bf((v[4] - mean) * inv) | ((uint)f2bf((v[5] - mean) * inv) << 16);
  o.w = (uint)f2bf((v[6] - mean) * inv) | ((uint)f2bf((v[7] - mean) * inv) << 16);
  *(uint4*)(Z + base) = o;
}

// ------------------------------------------------ K2: gate GEMM (K=1024, N=1536)
// 1-D grid (XCD-swizzled), K-loop split into two 512 halves, hoisted bases.
__global__ __launch_bounds__(256, 2) void k2_mfma(
    const ushort* __restrict__ Z, const ushort* __restrict__ Wt,
    const ushort* __restrict__ IL,
    const float* __restrict__ b0v, const float* __restrict__ b1v,
    const float* __restrict__ b2v,
    ushort* __restrict__ gates, int tc, int Tc, int nwg)
{
  __shared__ __align__(16) short As[128 * 32];
  __shared__ __align__(16) short Bs[128 * 32];
  const int tid = threadIdx.x;
  const int lane = tid & 63, wid = tid >> 6;
  // bijective XCD swizzle (nwg % 8 == 0 always: nwg = 12*64*nb)
  const int orig = blockIdx.x;
  const int cpx = nwg >> 3;
  const int swz = (orig & 7) * cpx + (orig >> 3);
  const int bx = swz % 12, by = swz / 12;
  const int nb = Tc >> 7;
  const int b = by / nb, tb = by % nb;
  const int r0g = b * 1024 + tc + tb * 128;
  const int r0c = b * Tc + tb * 128;
  const int n0 = bx * 128;
  const int wr = wid >> 1, wc = wid & 1;
  const int fr = lane & 15, fq = lane >> 4;
  const int srow = wid * 32 + (lane >> 2);
  const int scol = (lane & 3) * 8;

  const int rr0 = r0g + srow, rr1 = rr0 + 16;
  const ushort* a1_0 = Z + (size_t)rr0 * 512 + scol;
  const ushort* a1_1 = Z + (size_t)rr1 * 512 + scol;
  const ushort* a2_0 = (((rr0 & 1023) == 0) ? IL : (Z + (size_t)(rr0 - 1) * 512)) + scol;
  const ushort* a2_1 = (((rr1 & 1023) == 0) ? IL : (Z + (size_t)(rr1 - 1) * 512)) + scol;
  const ushort* b_0 = Wt + (size_t)(n0 + srow) * 1024 + scol;
  const ushort* b_1 = Wt + (size_t)(n0 + srow + 16) * 1024 + scol;

  f32x4 c00 = {0.f,0.f,0.f,0.f}, c01 = c00, c02 = c00, c03 = c00,
        c10 = c00, c11 = c00, c12 = c00, c13 = c00,
        c20 = c00, c21 = c00, c22 = c00, c23 = c00,
        c30 = c00, c31 = c00, c32 = c00, c33 = c00;

#define K2BODY \
    __syncthreads(); \
    { \
    const s16x8 a0 = *(const s16x8*)&As[(wr * 64 + 0 * 16 + fr) * 32 + fq * 8]; \
    const s16x8 a1 = *(const s16x8*)&As[(wr * 64 + 1 * 16 + fr) * 32 + fq * 8]; \
    const s16x8 a2 = *(const s16x8*)&As[(wr * 64 + 2 * 16 + fr) * 32 + fq * 8]; \
    const s16x8 a3 = *(const s16x8*)&As[(wr * 64 + 3 * 16 + fr) * 32 + fq * 8]; \
    const s16x8 b0 = *(const s16x8*)&Bs[(wc * 64 + 0 * 16 + fr) * 32 + fq * 8]; \
    const s16x8 b1 = *(const s16x8*)&Bs[(wc * 64 + 1 * 16 + fr) * 32 + fq * 8]; \
    const s16x8 b2 = *(const s16x8*)&Bs[(wc * 64 + 2 * 16 + fr) * 32 + fq * 8]; \
    const s16x8 b3 = *(const s16x8*)&Bs[(wc * 64 + 3 * 16 + fr) * 32 + fq * 8]; \
    MF(c00, a0, b0) MF(c01, a0, b1) MF(c02, a0, b2) MF(c03, a0, b3) \
    MF(c10, a1, b0) MF(c11, a1, b1) MF(c12, a1, b2) MF(c13, a1, b3) \
    MF(c20, a2, b0) MF(c21, a2, b1) MF(c22, a2, b2) MF(c23, a2, b3) \
    MF(c30, a3, b0) MF(c31, a3, b1) MF(c32, a3, b2) MF(c33, a3, b3) \
    } \
    __syncthreads();

  for (int k0 = 0; k0 < 512; k0 += 32) {
    gload_lds16(a1_0 + k0, &As[(wid * 32) * 32]);
    gload_lds16(a1_1 + k0, &As[(wid * 32 + 16) * 32]);
    gload_lds16(b_0 + k0, &Bs[(wid * 32) * 32]);
    gload_lds16(b_1 + k0, &Bs[(wid * 32 + 16) * 32]);
    K2BODY
  }
  for (int k0 = 0; k0 < 512; k0 += 32) {
    gload_lds16(a2_0 + k0, &As[(wid * 32) * 32]);
    gload_lds16(a2_1 + k0, &As[(wid * 32 + 16) * 32]);
    gload_lds16(b_0 + 512 + k0, &Bs[(wid * 32) * 32]);
    gload_lds16(b_1 + 512 + k0, &Bs[(wid * 32 + 16) * 32]);
    K2BODY
  }
#undef K2BODY

  const int sel = n0 >> 9;
  const float* bb = sel == 0 ? b0v : (sel == 1 ? b1v : b2v);
#define EPI(cmn, m_, n_) { \
    const int col = n0 + wc * 64 + n_ * 16 + fr; \
    const float bv = bb[col & 511]; \
    const int rbase = wr * 64 + m_ * 16 + fq * 4; \
    _Pragma("unroll") for (int j = 0; j < 4; ++j) { \
      const float uu = cmn[j] + bv; \
      const float vv = (sel < 2) ? (1.f / (1.f + __expf(-uu))) \
                                 : (2.f / (1.f + __expf(-2.f * uu)) - 1.f); \
      gates[(size_t)(r0c + rbase + j) * 1536 + col] = f2h(vv); } }
  EPI(c00, 0, 0) EPI(c01, 0, 1) EPI(c02, 0, 2) EPI(c03, 0, 3)
  EPI(c10, 1, 0) EPI(c11, 1, 1) EPI(c12, 1, 2) EPI(c13, 1, 3)
  EPI(c20, 2, 0) EPI(c21, 2, 1) EPI(c22, 2, 2) EPI(c23, 2, 3)
  EPI(c30, 3, 0) EPI(c31, 3, 1) EPI(c32, 3, 2) EPI(c33, 3, 3)
#undef EPI
}

// ------------------------------------------------ scan phase A: segment summaries
__global__ __launch_bounds__(256) void k3a_seg(
    const ushort* __restrict__ gates, float* __restrict__ Aseg,
    float* __restrict__ Bseg, int Tc)
{
  const int l = blockIdx.x * 256 + threadIdx.x;
  const int b = blockIdx.y, s = blockIdx.z;
  const int SEGc = Tc >> 6;
  const ushort* gb = gates + ((size_t)(b * Tc + s * 64)) * 1536 + l;
  float A = 1.f, c = 0.f;
#pragma unroll 8
  for (int j = 0; j < 64; ++j) {
    const float iv = h2f(gb[(size_t)j * 1536]);
    const float fv = h2f(gb[(size_t)j * 1536 + 512]);
    const float gv = h2f(gb[(size_t)j * 1536 + 1024]);
    A *= fv;
    c = fmaf(fv, c, iv * gv);
  }
  const size_t o = (size_t)(b * SEGc + s) * 512 + l;
  Aseg[o] = A;
  Bseg[o] = c;
}

// ------------------------------------------------ scan phase B: combine segments
__global__ __launch_bounds__(512) void k3b_comb(
    const float* __restrict__ Aseg, const float* __restrict__ Bseg,
    const float* __restrict__ initc, float* __restrict__ cstart,
    float* __restrict__ cbuf, int tc, int Tc)
{
  const int b = blockIdx.x, l = threadIdx.x;
  const int SEGc = Tc >> 6;
  float c = (tc == 0) ? initc[l] : cbuf[b * 512 + l];
  for (int s = 0; s < SEGc; ++s) {
    const size_t o = (size_t)(b * SEGc + s) * 512 + l;
    cstart[o] = c;
    c = fmaf(Aseg[o], c, Bseg[o]);
  }
  cbuf[b * 512 + l] = c;
}

// ------------------------------------------------ scan phase C: emit outputs
__global__ __launch_bounds__(128) void k3c_emit(
    const ushort* __restrict__ gates, const ushort* __restrict__ Z,
    const float* __restrict__ cstart, float* __restrict__ out,
    int tc, int Tc)
{
  __shared__ float tile[128][65];
  const int tid = threadIdx.x;
  const int l0 = blockIdx.x * 128;
  const int b = blockIdx.y, s = blockIdx.z;
  const int SEGc = Tc >> 6;
  const int l = l0 + tid;

  float c = cstart[(size_t)(b * SEGc + s) * 512 + l];
  const ushort* gb = gates + ((size_t)(b * Tc + s * 64)) * 1536 + l;
  const ushort* zb = Z + ((size_t)(b * 1024 + tc + s * 64)) * 512 + l;
#pragma unroll 8
  for (int j = 0; j < 64; ++j) {
    const float iv = h2f(gb[(size_t)j * 1536]);
    const float fv = h2f(gb[(size_t)j * 1536 + 512]);
    const float gv = h2f(gb[(size_t)j * 1536 + 1024]);
    const float zv = bf2f(zb[(size_t)j * 512]);
    c = fmaf(fv, c, iv * gv);
    tile[tid][j] = sinf(zv) * c;
  }
  __syncthreads();
  const int col = tid & 63, rhalf = tid >> 6;
  const size_t obase = ((size_t)b * 512 + l0) * 1024 + (size_t)(tc + s * 64) + col;
#pragma unroll
  for (int p = 0; p < 64; ++p) {
    const int row = rhalf + p * 2;
    out[obase + (size_t)row * 1024] = tile[row][col];
  }
}

// ------------------------------------------------ launcher
extern "C" void kernel_launch(void* const* d_in, const int* in_sizes, int n_in,
                              void* d_out, int out_size, void* d_ws, size_t ws_size,
                              hipStream_t stream)
{
  const float* x  = (const float*)d_in[0];
  const float* W  = (const float*)d_in[1];
  const float* rb = (const float*)d_in[2];
  const float* wi = (const float*)d_in[3];
  const float* wf = (const float*)d_in[4];
  const float* wc = (const float*)d_in[5];
  const float* ri = (const float*)d_in[6];
  const float* rf = (const float*)d_in[7];
  const float* rc = (const float*)d_in[8];
  const float* bi = (const float*)d_in[9];
  const float* bfo = (const float*)d_in[10];
  const float* bc = (const float*)d_in[11];
  const float* il = (const float*)d_in[12];
  const float* ic = (const float*)d_in[13];
  float* out = (float*)d_out;

  char* ws = (char*)d_ws;
  size_t off = 0;
  auto alloc = [&](size_t bytes) -> void* {
    void* p = ws + off;
    off = (off + bytes + 255) & ~(size_t)255;
    return p;
  };
  ushort* z    = (ushort*)alloc((size_t)65536 * 512 * 2);   // 67.1 MB
  ushort* W1t  = (ushort*)alloc((size_t)512 * 512 * 2);
  ushort* W2t  = (ushort*)alloc((size_t)1536 * 1024 * 2);
  ushort* ilb  = (ushort*)alloc(512 * 2);
  float*  cbuf = (float*)alloc((size_t)64 * 512 * 4);
  float*  Aseg = (float*)alloc((size_t)64 * 16 * 512 * 4);  // 2 MB
  float*  Bseg = (float*)alloc((size_t)64 * 16 * 512 * 4);
  float*  cstart = (float*)alloc((size_t)64 * 16 * 512 * 4);
  const size_t fixed_end = off;
  ushort* xt   = (ushort*)alloc((size_t)65536 * 512 * 2);   // dead after K1
  ushort* gates = (ushort*)(ws + fixed_end);                // aliases xt region
  ushort* u    = (ushort*)d_out;                            // dead before k3c

  int Tc = 1024;
  while (Tc > 128 && fixed_end + (size_t)64 * Tc * 1536 * 2 > ws_size) Tc >>= 1;

  // prep: weights
  transpose_cvt<<<dim3(16, 16, 1), 256, 0, stream>>>(W, 0, 512, W1t, 0, 512);
  const float* gw[6] = {wi, ri, wf, rf, wc, rc};
  for (int s = 0; s < 3; ++s) {
    transpose_cvt<<<dim3(16, 16, 1), 256, 0, stream>>>(
        gw[s * 2 + 0], 0, 512, W2t + (size_t)s * 512 * 1024, 0, 1024);
    transpose_cvt<<<dim3(16, 16, 1), 256, 0, stream>>>(
        gw[s * 2 + 1], 0, 512, W2t + (size_t)s * 512 * 1024 + 512, 0, 1024);
  }
  cvt_bf16<<<2, 256, 0, stream>>>(il, ilb, 512);
  transpose_cvt<<<dim3(32, 16, 64), 256, 0, stream>>>(
      x, (long long)512 * 1024, 1024, xt, (long long)1024 * 512, 512);

  k1_mfma<<<dim3(2048), 256, 0, stream>>>(xt, W1t, rb, u);
  ln_rows<<<16384, 256, 0, stream>>>(u, z);

  for (int tc = 0; tc < 1024; tc += Tc) {
    const int SEGc = Tc >> 6;
    const int nwg2 = 12 * 64 * (Tc >> 7);
    k2_mfma<<<dim3(nwg2), 256, 0, stream>>>(
        z, W2t, ilb, bi, bfo, bc, gates, tc, Tc, nwg2);
    k3a_seg<<<dim3(2, 64, SEGc), 256, 0, stream>>>(gates, Aseg, Bseg, Tc);
    k3b_comb<<<64, 512, 0, stream>>>(Aseg, Bseg, ic, cstart, cbuf, tc, Tc);
    k3c_emit<<<dim3(4, 64, SEGc), 128, 0, stream>>>(gates, z, cstart, out, tc, Tc);
  }
}

// Round 8
// 606.925 us; speedup vs baseline: 2.3590x; 1.0562x over previous
//
#include <hip/hip_runtime.h>
#include <hip/hip_bf16.h>
#include <hip/hip_fp16.h>
#include <cstdint>
#include <cstddef>

// B=64, D=512, T=1024, L=512
// prep:  xt[b][t][d] bf16 ; W1t[l][d] bf16 ; W2t[n=1536][k=1024] bf16 ; il bf16
// K1:    u = cos(xt @ rff_w + b)            (MFMA 128x128 BK=64 swizzled LDS)
// LN:    z = layernorm(u)                   (bf16, one wave per row)
// K2:    gates = act([z_t||z_prev] @ W2t^T) (MFMA 128x128 BK=64 swizzled, fp16)
// scan (segmented): k3a summaries -> k3b combine -> k3c emit + transpose
//
// LESSON (r4-r6): f32x4 acc arrays are NOT SROA-promoted -> scratch RMW. All
// accumulators/fragments are NAMED variables.
// LDS swizzle (T2/G4, rule #21 both-sides): physical 16B-chunk = logical chunk
// XOR (row&7); source pre-swizzled for global_load_lds (linear dest), ds_read
// applies the same XOR. 2-way residual aliasing = free (m136).

typedef float f32x4 __attribute__((ext_vector_type(4)));
typedef short s16x8 __attribute__((ext_vector_type(8)));

__device__ __forceinline__ void gload_lds16(const void* g, void* l) {
  __builtin_amdgcn_global_load_lds(
      (const __attribute__((address_space(1))) void*)g,
      (__attribute__((address_space(3))) void*)l, 16, 0, 0);
}
__device__ __forceinline__ ushort f2bf(float f) {
  uint32_t u = __float_as_uint(f);
  return (ushort)((u + 0x7FFF + ((u >> 16) & 1)) >> 16);  // RNE
}
__device__ __forceinline__ float bf2f(ushort s) {
  return __uint_as_float(((uint32_t)s) << 16);
}
__device__ __forceinline__ ushort f2h(float f) {
  return __half_as_ushort(__float2half(f));
}
__device__ __forceinline__ float h2f(ushort s) {
  return __half2float(__ushort_as_half(s));
}

#define MF(d, a, b) d = __builtin_amdgcn_mfma_f32_16x16x32_bf16(a, b, d, 0, 0, 0);

// ------------------------------------------------ prep: W1 transpose (small)
__global__ __launch_bounds__(256) void transpose_cvt(
    const float* __restrict__ src, ushort* __restrict__ dst, int ld)
{
  __shared__ float tile[32][33];
  const int c0 = blockIdx.x * 32, r0 = blockIdx.y * 32;
  const int tx = threadIdx.x & 31, ty = threadIdx.x >> 5;
#pragma unroll
  for (int i = 0; i < 4; ++i)
    tile[ty + i * 8][tx] = src[(size_t)(r0 + ty + i * 8) * 512 + c0 + tx];
  __syncthreads();
#pragma unroll
  for (int i = 0; i < 4; ++i)
    dst[(size_t)(c0 + ty + i * 8) * ld + r0 + tx] = f2bf(tile[tx][ty + i * 8]);
}

// ------------------------------------------------ prep: 6 gate weights + il in one launch
__global__ __launch_bounds__(256) void transpose6(
    const float* __restrict__ s0, const float* __restrict__ s1,
    const float* __restrict__ s2, const float* __restrict__ s3,
    const float* __restrict__ s4, const float* __restrict__ s5,
    const float* __restrict__ il, ushort* __restrict__ W2t,
    ushort* __restrict__ ilb)
{
  const int z = blockIdx.z;
  if (z == 6) {
    if (blockIdx.x == 0 && blockIdx.y == 0) {
      ilb[threadIdx.x] = f2bf(il[threadIdx.x]);
      ilb[threadIdx.x + 256] = f2bf(il[threadIdx.x + 256]);
    }
    return;
  }
  const float* src = z == 0 ? s0 : z == 1 ? s1 : z == 2 ? s2
                   : z == 3 ? s3 : z == 4 ? s4 : s5;
  ushort* dst = W2t + (size_t)(z >> 1) * 512 * 1024 + (z & 1) * 512;
  __shared__ float tile[32][33];
  const int c0 = blockIdx.x * 32, r0 = blockIdx.y * 32;
  const int tx = threadIdx.x & 31, ty = threadIdx.x >> 5;
#pragma unroll
  for (int i = 0; i < 4; ++i)
    tile[ty + i * 8][tx] = src[(size_t)(r0 + ty + i * 8) * 512 + c0 + tx];
  __syncthreads();
#pragma unroll
  for (int i = 0; i < 4; ++i)
    dst[(size_t)(c0 + ty + i * 8) * 1024 + r0 + tx] = f2bf(tile[tx][ty + i * 8]);
}

// ------------------------------------------------ prep: x[b][d][t] -> xt[b][t][d] bf16
// 64x64 tiles, float4 in / uint4 out.
__global__ __launch_bounds__(256) void transpose_x(
    const float* __restrict__ x, ushort* __restrict__ xt)
{
  __shared__ float tile[64][68];
  const int b = blockIdx.z;
  const int t0 = blockIdx.x * 64, d0 = blockIdx.y * 64;
  const float* src = x + ((size_t)b * 512 + d0) * 1024 + t0;
  const int lr_ = threadIdx.x >> 4, lc4 = (threadIdx.x & 15) * 4;
#pragma unroll
  for (int p = 0; p < 4; ++p) {
    const float4 v = *(const float4*)(src + (size_t)(lr_ + p * 16) * 1024 + lc4);
    *(float4*)&tile[lr_ + p * 16][lc4] = v;
  }
  __syncthreads();
  // NOTE: tile[d_local][t_local] holds x[d0+d][t0+t]... loaded rows are d, cols t.
  const int tt = threadIdx.x >> 2, dc = (threadIdx.x & 3) * 16;
  ushort* dst = xt + ((size_t)b * 1024 + t0 + tt) * 512 + d0 + dc;
  uint4 o1, o2;
  o1.x = (uint)f2bf(tile[dc + 0][tt]) | ((uint)f2bf(tile[dc + 1][tt]) << 16);
  o1.y = (uint)f2bf(tile[dc + 2][tt]) | ((uint)f2bf(tile[dc + 3][tt]) << 16);
  o1.z = (uint)f2bf(tile[dc + 4][tt]) | ((uint)f2bf(tile[dc + 5][tt]) << 16);
  o1.w = (uint)f2bf(tile[dc + 6][tt]) | ((uint)f2bf(tile[dc + 7][tt]) << 16);
  o2.x = (uint)f2bf(tile[dc + 8][tt]) | ((uint)f2bf(tile[dc + 9][tt]) << 16);
  o2.y = (uint)f2bf(tile[dc + 10][tt]) | ((uint)f2bf(tile[dc + 11][tt]) << 16);
  o2.z = (uint)f2bf(tile[dc + 12][tt]) | ((uint)f2bf(tile[dc + 13][tt]) << 16);
  o2.w = (uint)f2bf(tile[dc + 14][tt]) | ((uint)f2bf(tile[dc + 15][tt]) << 16);
  *(uint4*)(dst) = o1;
  *(uint4*)(dst + 8) = o2;
}

// ------------------------------------------------ K1: u = cos(xt@W1t^T + bias)
// 128x128 tile, BK=64, swizzled LDS. grid 2048 1-D, XCD-swizzled.
__global__ __launch_bounds__(256, 2) void k1_mfma(
    const ushort* __restrict__ A, const ushort* __restrict__ Bt,
    const float* __restrict__ bias, ushort* __restrict__ U)
{
  __shared__ __align__(16) short As[128 * 64];
  __shared__ __align__(16) short Bs[128 * 64];
  const int tid = threadIdx.x;
  const int lane = tid & 63, wid = tid >> 6;
  const int orig = blockIdx.x;
  const int swz = (orig & 7) * 256 + (orig >> 3);
  const int n0 = (swz & 3) * 128, r0 = (swz >> 2) * 128;
  const int wr = wid >> 1, wc = wid & 1;
  const int fr = lane & 15, fq = lane >> 4;
  const int lr = lane >> 3;                      // 0..7
  const int swz_el = ((lane & 7) ^ lr) * 8;      // pre-swizzled source k-offset

  const int RA = r0 + wid * 32 + lr;
  const ushort* pa0 = A + (size_t)(RA)      * 512 + swz_el;
  const ushort* pa1 = A + (size_t)(RA + 8)  * 512 + swz_el;
  const ushort* pa2 = A + (size_t)(RA + 16) * 512 + swz_el;
  const ushort* pa3 = A + (size_t)(RA + 24) * 512 + swz_el;
  const int RB = n0 + wid * 32 + lr;
  const ushort* pb0 = Bt + (size_t)(RB)      * 512 + swz_el;
  const ushort* pb1 = Bt + (size_t)(RB + 8)  * 512 + swz_el;
  const ushort* pb2 = Bt + (size_t)(RB + 16) * 512 + swz_el;
  const ushort* pb3 = Bt + (size_t)(RB + 24) * 512 + swz_el;
  char* dA = (char*)As + wid * 4096;
  char* dB = (char*)Bs + wid * 4096;

  const int so0 = fr * 64 + ((fq)     ^ (fr & 7)) * 8;   // ks=0 read offset (shorts)
  const int so1 = fr * 64 + ((4 + fq) ^ (fr & 7)) * 8;   // ks=1

  f32x4 c00 = {0.f,0.f,0.f,0.f}, c01 = c00, c02 = c00, c03 = c00,
        c10 = c00, c11 = c00, c12 = c00, c13 = c00,
        c20 = c00, c21 = c00, c22 = c00, c23 = c00,
        c30 = c00, c31 = c00, c32 = c00, c33 = c00;

  for (int k0 = 0; k0 < 512; k0 += 64) {
    gload_lds16(pa0 + k0, dA);        gload_lds16(pa1 + k0, dA + 1024);
    gload_lds16(pa2 + k0, dA + 2048); gload_lds16(pa3 + k0, dA + 3072);
    gload_lds16(pb0 + k0, dB);        gload_lds16(pb1 + k0, dB + 1024);
    gload_lds16(pb2 + k0, dB + 2048); gload_lds16(pb3 + k0, dB + 3072);
    __syncthreads();
    const s16x8 a00 = *(const s16x8*)&As[wr * 4096 + 0 * 1024 + so0];
    const s16x8 a01 = *(const s16x8*)&As[wr * 4096 + 0 * 1024 + so1];
    const s16x8 a10 = *(const s16x8*)&As[wr * 4096 + 1 * 1024 + so0];
    const s16x8 a11 = *(const s16x8*)&As[wr * 4096 + 1 * 1024 + so1];
    const s16x8 a20 = *(const s16x8*)&As[wr * 4096 + 2 * 1024 + so0];
    const s16x8 a21 = *(const s16x8*)&As[wr * 4096 + 2 * 1024 + so1];
    const s16x8 a30 = *(const s16x8*)&As[wr * 4096 + 3 * 1024 + so0];
    const s16x8 a31 = *(const s16x8*)&As[wr * 4096 + 3 * 1024 + so1];
    const s16x8 b00 = *(const s16x8*)&Bs[wc * 4096 + 0 * 1024 + so0];
    const s16x8 b01 = *(const s16x8*)&Bs[wc * 4096 + 0 * 1024 + so1];
    const s16x8 b10 = *(const s16x8*)&Bs[wc * 4096 + 1 * 1024 + so0];
    const s16x8 b11 = *(const s16x8*)&Bs[wc * 4096 + 1 * 1024 + so1];
    const s16x8 b20 = *(const s16x8*)&Bs[wc * 4096 + 2 * 1024 + so0];
    const s16x8 b21 = *(const s16x8*)&Bs[wc * 4096 + 2 * 1024 + so1];
    const s16x8 b30 = *(const s16x8*)&Bs[wc * 4096 + 3 * 1024 + so0];
    const s16x8 b31 = *(const s16x8*)&Bs[wc * 4096 + 3 * 1024 + so1];
    MF(c00, a00, b00) MF(c01, a00, b10) MF(c02, a00, b20) MF(c03, a00, b30)
    MF(c10, a10, b00) MF(c11, a10, b10) MF(c12, a10, b20) MF(c13, a10, b30)
    MF(c20, a20, b00) MF(c21, a20, b10) MF(c22, a20, b20) MF(c23, a20, b30)
    MF(c30, a30, b00) MF(c31, a30, b10) MF(c32, a30, b20) MF(c33, a30, b30)
    MF(c00, a01, b01) MF(c01, a01, b11) MF(c02, a01, b21) MF(c03, a01, b31)
    MF(c10, a11, b01) MF(c11, a11, b11) MF(c12, a11, b21) MF(c13, a11, b31)
    MF(c20, a21, b01) MF(c21, a21, b11) MF(c22, a21, b21) MF(c23, a21, b31)
    MF(c30, a31, b01) MF(c31, a31, b11) MF(c32, a31, b21) MF(c33, a31, b31)
    __syncthreads();
  }

#define EPI1(cmn, m_, n_) { \
    const int col = n0 + wc * 64 + n_ * 16 + fr; \
    const float bv = bias[col]; \
    const int rbase = r0 + wr * 64 + m_ * 16 + fq * 4; \
    _Pragma("unroll") for (int j = 0; j < 4; ++j) \
      U[(size_t)(rbase + j) * 512 + col] = f2bf(cosf(cmn[j] + bv)); }
  EPI1(c00, 0, 0) EPI1(c01, 0, 1) EPI1(c02, 0, 2) EPI1(c03, 0, 3)
  EPI1(c10, 1, 0) EPI1(c11, 1, 1) EPI1(c12, 1, 2) EPI1(c13, 1, 3)
  EPI1(c20, 2, 0) EPI1(c21, 2, 1) EPI1(c22, 2, 2) EPI1(c23, 2, 3)
  EPI1(c30, 3, 0) EPI1(c31, 3, 1) EPI1(c32, 3, 2) EPI1(c33, 3, 3)
#undef EPI1
}

// ------------------------------------------------ LN: one wave per 512-row
__global__ __launch_bounds__(256) void ln_rows(
    const ushort* __restrict__ U, ushort* __restrict__ Z)
{
  const int row = blockIdx.x * 4 + (threadIdx.x >> 6);
  const int lane = threadIdx.x & 63;
  const size_t base = (size_t)row * 512 + lane * 8;
  const uint4 pk = *(const uint4*)(U + base);
  float v[8];
  v[0] = bf2f(pk.x & 0xffff); v[1] = bf2f(pk.x >> 16);
  v[2] = bf2f(pk.y & 0xffff); v[3] = bf2f(pk.y >> 16);
  v[4] = bf2f(pk.z & 0xffff); v[5] = bf2f(pk.z >> 16);
  v[6] = bf2f(pk.w & 0xffff); v[7] = bf2f(pk.w >> 16);
  float s = 0.f, s2 = 0.f;
#pragma unroll
  for (int j = 0; j < 8; ++j) { s += v[j]; s2 += v[j] * v[j]; }
#pragma unroll
  for (int m = 1; m < 64; m <<= 1) { s += __shfl_xor(s, m); s2 += __shfl_xor(s2, m); }
  const float mean = s * (1.f / 512.f);
  const float var = s2 * (1.f / 512.f) - mean * mean;
  const float inv = rsqrtf(var + 1e-5f);
  uint4 o;
  o.x = (uint)f2bf((v[0] - mean) * inv) | ((uint)f2bf((v[1] - mean) * inv) << 16);
  o.y = (uint)f2bf((v[2] - mean) * inv) | ((uint)f2bf((v[3] - mean) * inv) << 16);
  o.z = (uint)f2bf((v[4] - mean) * inv) | ((uint)f2bf((v[5] - mean) * inv) << 16);
  o.w = (uint)f2bf((v[6] - mean) * inv) | ((uint)f2bf((v[7] - mean) * inv) << 16);
  *(uint4*)(Z + base) = o;
}

// ------------------------------------------------ K2: gate GEMM (K=1024, N=1536)
// 128x128 tile, BK=64 swizzled, two 512-halves (z_t then z_prev).
__global__ __launch_bounds__(256, 2) void k2_mfma(
    const ushort* __restrict__ Z, const ushort* __restrict__ Wt,
    const ushort* __restrict__ IL,
    const float* __restrict__ b0v, const float* __restrict__ b1v,
    const float* __restrict__ b2v,
    ushort* __restrict__ gates, int tc, int Tc, int nwg)
{
  __shared__ __align__(16) short As[128 * 64];
  __shared__ __align__(16) short Bs[128 * 64];
  const int tid = threadIdx.x;
  const int lane = tid & 63, wid = tid >> 6;
  const int cpx = nwg >> 3;
  const int orig = blockIdx.x;
  const int swz = (orig & 7) * cpx + (orig >> 3);
  const int bx = swz % 12, by = swz / 12;
  const int nb = Tc >> 7;
  const int b = by / nb, tb = by % nb;
  const int r0g = b * 1024 + tc + tb * 128;
  const int r0c = b * Tc + tb * 128;
  const int n0 = bx * 128;
  const int wr = wid >> 1, wc = wid & 1;
  const int fr = lane & 15, fq = lane >> 4;
  const int lr = lane >> 3;
  const int swz_el = ((lane & 7) ^ lr) * 8;

  const int R0 = r0g + wid * 32 + lr;
  const ushort* pa0 = Z + (size_t)(R0)      * 512 + swz_el;
  const ushort* pa1 = Z + (size_t)(R0 + 8)  * 512 + swz_el;
  const ushort* pa2 = Z + (size_t)(R0 + 16) * 512 + swz_el;
  const ushort* pa3 = Z + (size_t)(R0 + 24) * 512 + swz_el;
  const ushort* ph0 = ((((R0)      & 1023) == 0) ? IL : (Z + (size_t)(R0 - 1)  * 512)) + swz_el;
  const ushort* ph1 = ((((R0 + 8)  & 1023) == 0) ? IL : (Z + (size_t)(R0 + 7)  * 512)) + swz_el;
  const ushort* ph2 = ((((R0 + 16) & 1023) == 0) ? IL : (Z + (size_t)(R0 + 15) * 512)) + swz_el;
  const ushort* ph3 = ((((R0 + 24) & 1023) == 0) ? IL : (Z + (size_t)(R0 + 23) * 512)) + swz_el;
  const int RB = n0 + wid * 32 + lr;
  const ushort* pb0 = Wt + (size_t)(RB)      * 1024 + swz_el;
  const ushort* pb1 = Wt + (size_t)(RB + 8)  * 1024 + swz_el;
  const ushort* pb2 = Wt + (size_t)(RB + 16) * 1024 + swz_el;
  const ushort* pb3 = Wt + (size_t)(RB + 24) * 1024 + swz_el;
  char* dA = (char*)As + wid * 4096;
  char* dB = (char*)Bs + wid * 4096;

  const int so0 = fr * 64 + ((fq)     ^ (fr & 7)) * 8;
  const int so1 = fr * 64 + ((4 + fq) ^ (fr & 7)) * 8;

  f32x4 c00 = {0.f,0.f,0.f,0.f}, c01 = c00, c02 = c00, c03 = c00,
        c10 = c00, c11 = c00, c12 = c00, c13 = c00,
        c20 = c00, c21 = c00, c22 = c00, c23 = c00,
        c30 = c00, c31 = c00, c32 = c00, c33 = c00;

#define K2BODY \
    __syncthreads(); \
    { \
    const s16x8 a00 = *(const s16x8*)&As[wr * 4096 + 0 * 1024 + so0]; \
    const s16x8 a01 = *(const s16x8*)&As[wr * 4096 + 0 * 1024 + so1]; \
    const s16x8 a10 = *(const s16x8*)&As[wr * 4096 + 1 * 1024 + so0]; \
    const s16x8 a11 = *(const s16x8*)&As[wr * 4096 + 1 * 1024 + so1]; \
    const s16x8 a20 = *(const s16x8*)&As[wr * 4096 + 2 * 1024 + so0]; \
    const s16x8 a21 = *(const s16x8*)&As[wr * 4096 + 2 * 1024 + so1]; \
    const s16x8 a30 = *(const s16x8*)&As[wr * 4096 + 3 * 1024 + so0]; \
    const s16x8 a31 = *(const s16x8*)&As[wr * 4096 + 3 * 1024 + so1]; \
    const s16x8 b00 = *(const s16x8*)&Bs[wc * 4096 + 0 * 1024 + so0]; \
    const s16x8 b01 = *(const s16x8*)&Bs[wc * 4096 + 0 * 1024 + so1]; \
    const s16x8 b10 = *(const s16x8*)&Bs[wc * 4096 + 1 * 1024 + so0]; \
    const s16x8 b11 = *(const s16x8*)&Bs[wc * 4096 + 1 * 1024 + so1]; \
    const s16x8 b20 = *(const s16x8*)&Bs[wc * 4096 + 2 * 1024 + so0]; \
    const s16x8 b21 = *(const s16x8*)&Bs[wc * 4096 + 2 * 1024 + so1]; \
    const s16x8 b30 = *(const s16x8*)&Bs[wc * 4096 + 3 * 1024 + so0]; \
    const s16x8 b31 = *(const s16x8*)&Bs[wc * 4096 + 3 * 1024 + so1]; \
    MF(c00, a00, b00) MF(c01, a00, b10) MF(c02, a00, b20) MF(c03, a00, b30) \
    MF(c10, a10, b00) MF(c11, a10, b10) MF(c12, a10, b20) MF(c13, a10, b30) \
    MF(c20, a20, b00) MF(c21, a20, b10) MF(c22, a20, b20) MF(c23, a20, b30) \
    MF(c30, a30, b00) MF(c31, a30, b10) MF(c32, a30, b20) MF(c33, a30, b30) \
    MF(c00, a01, b01) MF(c01, a01, b11) MF(c02, a01, b21) MF(c03, a01, b31) \
    MF(c10, a11, b01) MF(c11, a11, b11) MF(c12, a11, b21) MF(c13, a11, b31) \
    MF(c20, a21, b01) MF(c21, a21, b11) MF(c22, a21, b21) MF(c23, a21, b31) \
    MF(c30, a31, b01) MF(c31, a31, b11) MF(c32, a31, b21) MF(c33, a31, b31) \
    } \
    __syncthreads();

  for (int k0 = 0; k0 < 512; k0 += 64) {
    gload_lds16(pa0 + k0, dA);        gload_lds16(pa1 + k0, dA + 1024);
    gload_lds16(pa2 + k0, dA + 2048); gload_lds16(pa3 + k0, dA + 3072);
    gload_lds16(pb0 + k0, dB);        gload_lds16(pb1 + k0, dB + 1024);
    gload_lds16(pb2 + k0, dB + 2048); gload_lds16(pb3 + k0, dB + 3072);
    K2BODY
  }
  for (int k0 = 0; k0 < 512; k0 += 64) {
    gload_lds16(ph0 + k0, dA);        gload_lds16(ph1 + k0, dA + 1024);
    gload_lds16(ph2 + k0, dA + 2048); gload_lds16(ph3 + k0, dA + 3072);
    gload_lds16(pb0 + 512 + k0, dB);        gload_lds16(pb1 + 512 + k0, dB + 1024);
    gload_lds16(pb2 + 512 + k0, dB + 2048); gload_lds16(pb3 + 512 + k0, dB + 3072);
    K2BODY
  }
#undef K2BODY

  const int sel = n0 >> 9;
  const float* bb = sel == 0 ? b0v : (sel == 1 ? b1v : b2v);
#define EPI(cmn, m_, n_) { \
    const int col = n0 + wc * 64 + n_ * 16 + fr; \
    const float bv = bb[col & 511]; \
    const int rbase = wr * 64 + m_ * 16 + fq * 4; \
    _Pragma("unroll") for (int j = 0; j < 4; ++j) { \
      const float uu = cmn[j] + bv; \
      const float vv = (sel < 2) ? (1.f / (1.f + __expf(-uu))) \
                                 : (2.f / (1.f + __expf(-2.f * uu)) - 1.f); \
      gates[(size_t)(r0c + rbase + j) * 1536 + col] = f2h(vv); } }
  EPI(c00, 0, 0) EPI(c01, 0, 1) EPI(c02, 0, 2) EPI(c03, 0, 3)
  EPI(c10, 1, 0) EPI(c11, 1, 1) EPI(c12, 1, 2) EPI(c13, 1, 3)
  EPI(c20, 2, 0) EPI(c21, 2, 1) EPI(c22, 2, 2) EPI(c23, 2, 3)
  EPI(c30, 3, 0) EPI(c31, 3, 1) EPI(c32, 3, 2) EPI(c33, 3, 3)
#undef EPI
}

// ------------------------------------------------ scan phase A: segment summaries
__global__ __launch_bounds__(256) void k3a_seg(
    const ushort* __restrict__ gates, float* __restrict__ Aseg,
    float* __restrict__ Bseg, int Tc)
{
  const int l = blockIdx.x * 256 + threadIdx.x;
  const int b = blockIdx.y, s = blockIdx.z;
  const int SEGc = Tc >> 6;
  const ushort* gb = gates + ((size_t)(b * Tc + s * 64)) * 1536 + l;
  float A = 1.f, c = 0.f;
#pragma unroll 8
  for (int j = 0; j < 64; ++j) {
    const float iv = h2f(gb[(size_t)j * 1536]);
    const float fv = h2f(gb[(size_t)j * 1536 + 512]);
    const float gv = h2f(gb[(size_t)j * 1536 + 1024]);
    A *= fv;
    c = fmaf(fv, c, iv * gv);
  }
  const size_t o = (size_t)(b * SEGc + s) * 512 + l;
  Aseg[o] = A;
  Bseg[o] = c;
}

// ------------------------------------------------ scan phase B: combine segments
__global__ __launch_bounds__(512) void k3b_comb(
    const float* __restrict__ Aseg, const float* __restrict__ Bseg,
    const float* __restrict__ initc, float* __restrict__ cstart,
    float* __restrict__ cbuf, int tc, int Tc)
{
  const int b = blockIdx.x, l = threadIdx.x;
  const int SEGc = Tc >> 6;
  float c = (tc == 0) ? initc[l] : cbuf[b * 512 + l];
  for (int s = 0; s < SEGc; ++s) {
    const size_t o = (size_t)(b * SEGc + s) * 512 + l;
    cstart[o] = c;
    c = fmaf(Aseg[o], c, Bseg[o]);
  }
  cbuf[b * 512 + l] = c;
}

// ------------------------------------------------ scan phase C: emit outputs
__global__ __launch_bounds__(128) void k3c_emit(
    const ushort* __restrict__ gates, const ushort* __restrict__ Z,
    const float* __restrict__ cstart, float* __restrict__ out,
    int tc, int Tc)
{
  __shared__ float tile[128][65];
  const int tid = threadIdx.x;
  const int l0 = blockIdx.x * 128;
  const int b = blockIdx.y, s = blockIdx.z;
  const int SEGc = Tc >> 6;
  const int l = l0 + tid;

  float c = cstart[(size_t)(b * SEGc + s) * 512 + l];
  const ushort* gb = gates + ((size_t)(b * Tc + s * 64)) * 1536 + l;
  const ushort* zb = Z + ((size_t)(b * 1024 + tc + s * 64)) * 512 + l;
#pragma unroll 8
  for (int j = 0; j < 64; ++j) {
    const float iv = h2f(gb[(size_t)j * 1536]);
    const float fv = h2f(gb[(size_t)j * 1536 + 512]);
    const float gv = h2f(gb[(size_t)j * 1536 + 1024]);
    const float zv = bf2f(zb[(size_t)j * 512]);
    c = fmaf(fv, c, iv * gv);
    tile[tid][j] = sinf(zv) * c;
  }
  __syncthreads();
  const int col = tid & 63, rhalf = tid >> 6;
  const size_t obase = ((size_t)b * 512 + l0) * 1024 + (size_t)(tc + s * 64) + col;
#pragma unroll
  for (int p = 0; p < 64; ++p) {
    const int row = rhalf + p * 2;
    out[obase + (size_t)row * 1024] = tile[row][col];
  }
}

// ------------------------------------------------ launcher
extern "C" void kernel_launch(void* const* d_in, const int* in_sizes, int n_in,
                              void* d_out, int out_size, void* d_ws, size_t ws_size,
                              hipStream_t stream)
{
  const float* x  = (const float*)d_in[0];
  const float* W  = (const float*)d_in[1];
  const float* rb = (const float*)d_in[2];
  const float* wi = (const float*)d_in[3];
  const float* wf = (const float*)d_in[4];
  const float* wc = (const float*)d_in[5];
  const float* ri = (const float*)d_in[6];
  const float* rf = (const float*)d_in[7];
  const float* rc = (const float*)d_in[8];
  const float* bi = (const float*)d_in[9];
  const float* bfo = (const float*)d_in[10];
  const float* bc = (const float*)d_in[11];
  const float* il = (const float*)d_in[12];
  const float* ic = (const float*)d_in[13];
  float* out = (float*)d_out;

  char* ws = (char*)d_ws;
  size_t off = 0;
  auto alloc = [&](size_t bytes) -> void* {
    void* p = ws + off;
    off = (off + bytes + 255) & ~(size_t)255;
    return p;
  };
  ushort* z    = (ushort*)alloc((size_t)65536 * 512 * 2);   // 67.1 MB
  ushort* W1t  = (ushort*)alloc((size_t)512 * 512 * 2);
  ushort* W2t  = (ushort*)alloc((size_t)1536 * 1024 * 2);
  ushort* ilb  = (ushort*)alloc(512 * 2);
  float*  cbuf = (float*)alloc((size_t)64 * 512 * 4);
  float*  Aseg = (float*)alloc((size_t)64 * 16 * 512 * 4);  // 2 MB
  float*  Bseg = (float*)alloc((size_t)64 * 16 * 512 * 4);
  float*  cstart = (float*)alloc((size_t)64 * 16 * 512 * 4);
  const size_t fixed_end = off;
  ushort* xt   = (ushort*)alloc((size_t)65536 * 512 * 2);   // dead after K1
  ushort* gates = (ushort*)(ws + fixed_end);                // aliases xt region
  ushort* u    = (ushort*)d_out;                            // dead before k3c

  int Tc = 1024;
  while (Tc > 128 && fixed_end + (size_t)64 * Tc * 1536 * 2 > ws_size) Tc >>= 1;

  // prep
  transpose_cvt<<<dim3(16, 16), 256, 0, stream>>>(W, W1t, 512);
  transpose6<<<dim3(16, 16, 7), 256, 0, stream>>>(wi, ri, wf, rf, wc, rc, il, W2t, ilb);
  transpose_x<<<dim3(16, 8, 64), 256, 0, stream>>>(x, xt);

  k1_mfma<<<dim3(2048), 256, 0, stream>>>(xt, W1t, rb, u);
  ln_rows<<<16384, 256, 0, stream>>>(u, z);

  for (int tc = 0; tc < 1024; tc += Tc) {
    const int SEGc = Tc >> 6;
    const int nwg2 = 12 * 64 * (Tc >> 7);
    k2_mfma<<<dim3(nwg2), 256, 0, stream>>>(
        z, W2t, ilb, bi, bfo, bc, gates, tc, Tc, nwg2);
    k3a_seg<<<dim3(2, 64, SEGc), 256, 0, stream>>>(gates, Aseg, Bseg, Tc);
    k3b_comb<<<64, 512, 0, stream>>>(Aseg, Bseg, ic, cstart, cbuf, tc, Tc);
    k3c_emit<<<dim3(4, 64, SEGc), 128, 0, stream>>>(gates, z, cstart, out, tc, Tc);
  }
}